// Round 1
// baseline (1201.010 us; speedup 1.0000x reference)
//
#include <hip/hip_runtime.h>

#define BN_EPS 1e-5f

// ---------------- graph structure kernels ----------------

__global__ __launch_bounds__(256) void count_kernel(const int* __restrict__ dst, int E,
                                                    int* __restrict__ counts) {
  int e = blockIdx.x * 256 + threadIdx.x;
  if (e < E) atomicAdd(&counts[dst[e]], 1);
}

__global__ __launch_bounds__(256) void dinv_kernel(const int* __restrict__ counts, int N,
                                                   float* __restrict__ dinv) {
  int n = blockIdx.x * 256 + threadIdx.x;
  if (n < N) dinv[n] = rsqrtf((float)(counts[n] + 1));  // +1 self loop; always >= 1
}

// exclusive scan of counts -> offs, chunked 1024/block
__global__ __launch_bounds__(256) void scan1(const int* __restrict__ counts, int N,
                                             int* __restrict__ offs, int* __restrict__ blkSum) {
  __shared__ int sd[256];
  int t = threadIdx.x;
  int i0 = blockIdx.x * 1024 + t * 4;
  int v0 = (i0 + 0 < N) ? counts[i0 + 0] : 0;
  int v1 = (i0 + 1 < N) ? counts[i0 + 1] : 0;
  int v2 = (i0 + 2 < N) ? counts[i0 + 2] : 0;
  int v3 = (i0 + 3 < N) ? counts[i0 + 3] : 0;
  int tot = v0 + v1 + v2 + v3;
  sd[t] = tot;
  __syncthreads();
  for (int off = 1; off < 256; off <<= 1) {
    int x = (t >= off) ? sd[t - off] : 0;
    __syncthreads();
    sd[t] += x;
    __syncthreads();
  }
  int excl = sd[t] - tot;
  if (i0 + 0 < N) offs[i0 + 0] = excl;
  if (i0 + 1 < N) offs[i0 + 1] = excl + v0;
  if (i0 + 2 < N) offs[i0 + 2] = excl + v0 + v1;
  if (i0 + 3 < N) offs[i0 + 3] = excl + v0 + v1 + v2;
  if (t == 255) blkSum[blockIdx.x] = sd[255];
}

__global__ void scan2(const int* __restrict__ blkSum, int nb, int* __restrict__ blkOff,
                      int* __restrict__ offs, int N) {
  if (threadIdx.x == 0 && blockIdx.x == 0) {
    int run = 0;
    for (int b = 0; b < nb; ++b) { blkOff[b] = run; run += blkSum[b]; }
    offs[N] = run;
  }
}

__global__ __launch_bounds__(1024) void scan3(int* __restrict__ offs, int N,
                                              const int* __restrict__ blkOff) {
  int i = blockIdx.x * 1024 + threadIdx.x;
  if (i < N) offs[i] += blkOff[blockIdx.x];
}

__global__ __launch_bounds__(256) void fill_kernel(const int* __restrict__ src,
                                                   const int* __restrict__ dst, int E,
                                                   const int* __restrict__ offs,
                                                   int* __restrict__ cursor,
                                                   const float* __restrict__ dinv,
                                                   int* __restrict__ csr_src,
                                                   float* __restrict__ csr_coef) {
  int e = blockIdx.x * 256 + threadIdx.x;
  if (e >= E) return;
  int s = src[e], d = dst[e];
  int pos = offs[d] + atomicAdd(&cursor[d], 1);
  csr_src[pos]  = s;
  csr_coef[pos] = dinv[s] * dinv[d];
}

// ---------------- aggregation (gather, CSR by dst), one wave per node ----------------

__global__ __launch_bounds__(256) void agg256(const float* __restrict__ h,
                                              const int* __restrict__ offs,
                                              const int* __restrict__ csr_src,
                                              const float* __restrict__ csr_coef,
                                              const float* __restrict__ dinv,
                                              float* __restrict__ out, int N) {
  int n = (blockIdx.x * 256 + threadIdx.x) >> 6;
  int lane = threadIdx.x & 63;
  if (n >= N) return;
  float di = dinv[n];
  const float4* hn = (const float4*)(h + (size_t)n * 256) + lane;
  float4 acc = *hn;
  float self = di * di;
  acc.x *= self; acc.y *= self; acc.z *= self; acc.w *= self;
  int e0 = offs[n], e1 = offs[n + 1];
  for (int eb = e0; eb < e1; eb += 64) {
    int k = min(64, e1 - eb);
    int sv = 0; float cv = 0.f;
    if (lane < k) { sv = csr_src[eb + lane]; cv = csr_coef[eb + lane]; }
    for (int i = 0; i < k; ++i) {
      int s = __shfl(sv, i);
      float co = __shfl(cv, i);
      float4 v = *((const float4*)(h + (size_t)s * 256) + lane);
      acc.x += co * v.x; acc.y += co * v.y; acc.z += co * v.z; acc.w += co * v.w;
    }
  }
  *((float4*)(out + (size_t)n * 256) + lane) = acc;
}

__global__ __launch_bounds__(256) void agg128(const float* __restrict__ h,
                                              const int* __restrict__ offs,
                                              const int* __restrict__ csr_src,
                                              const float* __restrict__ csr_coef,
                                              const float* __restrict__ dinv,
                                              float* __restrict__ out, int N) {
  int n = (blockIdx.x * 256 + threadIdx.x) >> 6;
  int lane = threadIdx.x & 63;
  if (n >= N) return;
  float di = dinv[n];
  const float2* hn = (const float2*)(h + (size_t)n * 128) + lane;
  float2 acc = *hn;
  float self = di * di;
  acc.x *= self; acc.y *= self;
  int e0 = offs[n], e1 = offs[n + 1];
  for (int eb = e0; eb < e1; eb += 64) {
    int k = min(64, e1 - eb);
    int sv = 0; float cv = 0.f;
    if (lane < k) { sv = csr_src[eb + lane]; cv = csr_coef[eb + lane]; }
    for (int i = 0; i < k; ++i) {
      int s = __shfl(sv, i);
      float co = __shfl(cv, i);
      float2 v = *((const float2*)(h + (size_t)s * 128) + lane);
      acc.x += co * v.x; acc.y += co * v.y;
    }
  }
  *((float2*)(out + (size_t)n * 128) + lane) = acc;
}

// ---------------- f32 GEMM: C[M,256] = A[M,K] @ W[K,256] ----------------
// 64x64 tile, BK=16, 256 threads, 4x4 per thread.

__global__ __launch_bounds__(256) void gemm_kernel(const float* __restrict__ A,
                                                   const float* __restrict__ W,
                                                   float* __restrict__ C, int M, int K) {
  __shared__ float As[16][64];
  __shared__ float Ws[16][64];
  int t = threadIdx.x;
  int tx = t & 15, ty = t >> 4;
  int rowBase = blockIdx.x * 64, colBase = blockIdx.y * 64;
  float acc[4][4] = {};
  for (int k0 = 0; k0 < K; k0 += 16) {
    {
      int r = t >> 2;           // 0..63
      int kk = (t & 3) * 4;     // 0,4,8,12
      int gr = rowBase + r;
      float4 v = make_float4(0.f, 0.f, 0.f, 0.f);
      if (gr < M) v = *(const float4*)&A[(size_t)gr * K + k0 + kk];
      As[kk + 0][r] = v.x; As[kk + 1][r] = v.y; As[kk + 2][r] = v.z; As[kk + 3][r] = v.w;
      int kr = t >> 4;          // 0..15
      int c = (t & 15) * 4;     // 0..60
      *(float4*)&Ws[kr][c] = *(const float4*)&W[(size_t)(k0 + kr) * 256 + colBase + c];
    }
    __syncthreads();
#pragma unroll
    for (int k = 0; k < 16; ++k) {
      float4 a = *(const float4*)&As[k][ty * 4];
      float4 b = *(const float4*)&Ws[k][tx * 4];
      acc[0][0] += a.x * b.x; acc[0][1] += a.x * b.y; acc[0][2] += a.x * b.z; acc[0][3] += a.x * b.w;
      acc[1][0] += a.y * b.x; acc[1][1] += a.y * b.y; acc[1][2] += a.y * b.z; acc[1][3] += a.y * b.w;
      acc[2][0] += a.z * b.x; acc[2][1] += a.z * b.y; acc[2][2] += a.z * b.z; acc[2][3] += a.z * b.w;
      acc[3][0] += a.w * b.x; acc[3][1] += a.w * b.y; acc[3][2] += a.w * b.z; acc[3][3] += a.w * b.w;
    }
    __syncthreads();
  }
#pragma unroll
  for (int i = 0; i < 4; ++i) {
    int gr = rowBase + ty * 4 + i;
    if (gr < M) {
      float4 v = make_float4(acc[i][0], acc[i][1], acc[i][2], acc[i][3]);
      *(float4*)&C[(size_t)gr * 256 + colBase + tx * 4] = v;
    }
  }
}

// ---------------- batchnorm ----------------

__global__ __launch_bounds__(256) void bn_stats(const float* __restrict__ h, int N,
                                                float* __restrict__ sums,
                                                float* __restrict__ sumsq) {
  int c = threadIdx.x;
  int rpb = (N + gridDim.x - 1) / gridDim.x;
  int r0 = blockIdx.x * rpb;
  int r1 = min(N, r0 + rpb);
  float s = 0.f, s2 = 0.f;
  for (int r = r0; r < r1; ++r) {
    float v = h[(size_t)r * 256 + c];
    s += v; s2 += v * v;
  }
  atomicAdd(&sums[c], s);
  atomicAdd(&sumsq[c], s2);
}

__global__ void bn_finalize(const float* __restrict__ sums, const float* __restrict__ sumsq,
                            const float* __restrict__ gamma, const float* __restrict__ beta,
                            int N, float* __restrict__ scale, float* __restrict__ shift) {
  int c = threadIdx.x;  // 256
  float inv_n = 1.0f / (float)N;
  float mean = sums[c] * inv_n;
  float var = sumsq[c] * inv_n - mean * mean;
  float sc = gamma[c] * rsqrtf(var + BN_EPS);
  scale[c] = sc;
  shift[c] = beta[c] - mean * sc;
}

__global__ __launch_bounds__(256) void bn_apply(float* __restrict__ h, int total4,
                                                const float* __restrict__ scale,
                                                const float* __restrict__ shift) {
  int idx = blockIdx.x * 256 + threadIdx.x;
  if (idx >= total4) return;
  int c4 = (idx & 63) * 4;
  float4 v = ((const float4*)h)[idx];
  float4 sc = *(const float4*)&scale[c4];
  float4 sh = *(const float4*)&shift[c4];
  v.x = fmaxf(v.x * sc.x + sh.x, 0.f);
  v.y = fmaxf(v.y * sc.y + sh.y, 0.f);
  v.z = fmaxf(v.z * sc.z + sh.z, 0.f);
  v.w = fmaxf(v.w * sc.w + sh.w, 0.f);
  ((float4*)h)[idx] = v;
}

// ---------------- pooling + classifier ----------------

__global__ __launch_bounds__(256) void cnt_kernel(const int* __restrict__ batch, int N,
                                                  int* __restrict__ cnt) {
  int i = blockIdx.x * 256 + threadIdx.x;
  if (i < N) atomicAdd(&cnt[batch[i]], 1);
}

__global__ __launch_bounds__(256) void pool_kernel(const float* __restrict__ h,
                                                   const int* __restrict__ batch, int N,
                                                   float* __restrict__ pool) {
  int c = threadIdx.x;
  int rpb = (N + gridDim.x - 1) / gridDim.x;
  int r0 = blockIdx.x * rpb;
  int r1 = min(N, r0 + rpb);
  if (r0 >= r1) return;
  float acc = 0.f;
  int cur = batch[r0];
  for (int r = r0; r < r1; ++r) {
    int g = batch[r];
    if (g != cur) { atomicAdd(&pool[(size_t)cur * 256 + c], acc); acc = 0.f; cur = g; }
    acc += h[(size_t)r * 256 + c];
  }
  atomicAdd(&pool[(size_t)cur * 256 + c], acc);
}

__global__ __launch_bounds__(64) void final_kernel(const float* __restrict__ pool,
                                                   const int* __restrict__ cnt,
                                                   const float* __restrict__ Wl,
                                                   const float* __restrict__ bl,
                                                   float* __restrict__ out, int NC) {
  __shared__ float p[256];
  int g = blockIdx.x, t = threadIdx.x;
  float inv = 1.0f / fmaxf((float)cnt[g], 1.0f);
  for (int i = t; i < 256; i += 64) p[i] = pool[(size_t)g * 256 + i] * inv;
  __syncthreads();
  if (t < NC) {
    float s = bl[t];
    for (int k = 0; k < 256; ++k) s += p[k] * Wl[k * NC + t];
    out[g * NC + t] = s;
  }
}

// ---------------- launcher ----------------

extern "C" void kernel_launch(void* const* d_in, const int* in_sizes, int n_in,
                              void* d_out, int out_size, void* d_ws, size_t ws_size,
                              hipStream_t stream) {
  const float* x      = (const float*)d_in[0];
  const int*   ei     = (const int*)d_in[1];
  const int*   batch  = (const int*)d_in[2];
  const float* W0     = (const float*)d_in[3];
  const float* gamma0 = (const float*)d_in[5];
  const float* beta0  = (const float*)d_in[6];
  const float* W1     = (const float*)d_in[7];
  const float* gamma1 = (const float*)d_in[9];
  const float* beta1  = (const float*)d_in[10];
  const float* W2     = (const float*)d_in[11];
  const float* gamma2 = (const float*)d_in[13];
  const float* beta2  = (const float*)d_in[14];
  const float* Wl     = (const float*)d_in[15];
  const float* bl     = (const float*)d_in[16];
  float* out = (float*)d_out;

  int N = in_sizes[0] / 128;  // 50000
  int E = in_sizes[1] / 2;    // 800000
  int G = 128;
  int NC = 40;
  const int* src = ei;
  const int* dst = ei + E;

  char* p = (char*)d_ws;
  auto alloc = [&](size_t bytes) -> void* {
    void* r = (void*)p;
    p += (bytes + 255) & ~(size_t)255;
    return r;
  };
  float* bufA     = (float*)alloc((size_t)N * 256 * 4);
  float* bufB     = (float*)alloc((size_t)N * 256 * 4);
  int*   csr_src  = (int*)  alloc((size_t)E * 4);
  float* csr_coef = (float*)alloc((size_t)E * 4);
  int*   counts   = (int*)  alloc((size_t)N * 4);
  int*   cursor   = (int*)  alloc((size_t)N * 4);
  int*   offs     = (int*)  alloc((size_t)(N + 1) * 4);
  float* dinv     = (float*)alloc((size_t)N * 4);
  int*   blkSum   = (int*)  alloc(64 * 4);
  int*   blkOff   = (int*)  alloc(64 * 4);
  float* sums     = (float*)alloc(512 * 4);   // sums[256] + sumsq[256], one memset
  float* sumsq    = sums + 256;
  float* scale    = (float*)alloc(256 * 4);
  float* shift    = (float*)alloc(256 * 4);
  float* pool     = (float*)alloc((size_t)G * 256 * 4);
  int*   cnt      = (int*)  alloc(G * 4);

  // ---- graph structure (once per launch) ----
  hipMemsetAsync(counts, 0, (size_t)N * 4, stream);
  hipMemsetAsync(cursor, 0, (size_t)N * 4, stream);
  count_kernel<<<(E + 255) / 256, 256, 0, stream>>>(dst, E, counts);
  dinv_kernel<<<(N + 255) / 256, 256, 0, stream>>>(counts, N, dinv);
  int nb = (N + 1023) / 1024;
  scan1<<<nb, 256, 0, stream>>>(counts, N, offs, blkSum);
  scan2<<<1, 1, 0, stream>>>(blkSum, nb, blkOff, offs, N);
  scan3<<<nb, 1024, 0, stream>>>(offs, N, blkOff);
  fill_kernel<<<(E + 255) / 256, 256, 0, stream>>>(src, dst, E, offs, cursor, dinv,
                                                   csr_src, csr_coef);

  int aggBlocks = (N + 3) / 4;
  dim3 gemmGrid((N + 63) / 64, 4);

  // ---- layer 0 (input x: 128 ch). Agg first (cheaper), bias cancels under BN. ----
  agg128<<<aggBlocks, 256, 0, stream>>>(x, offs, csr_src, csr_coef, dinv, bufA, N);
  gemm_kernel<<<gemmGrid, 256, 0, stream>>>(bufA, W0, bufB, N, 128);
  hipMemsetAsync(sums, 0, 512 * 4, stream);
  bn_stats<<<256, 256, 0, stream>>>(bufB, N, sums, sumsq);
  bn_finalize<<<1, 256, 0, stream>>>(sums, sumsq, gamma0, beta0, N, scale, shift);
  bn_apply<<<(N * 64 + 255) / 256, 256, 0, stream>>>(bufB, N * 64, scale, shift);

  // ---- layer 1 ----
  agg256<<<aggBlocks, 256, 0, stream>>>(bufB, offs, csr_src, csr_coef, dinv, bufA, N);
  gemm_kernel<<<gemmGrid, 256, 0, stream>>>(bufA, W1, bufB, N, 256);
  hipMemsetAsync(sums, 0, 512 * 4, stream);
  bn_stats<<<256, 256, 0, stream>>>(bufB, N, sums, sumsq);
  bn_finalize<<<1, 256, 0, stream>>>(sums, sumsq, gamma1, beta1, N, scale, shift);
  bn_apply<<<(N * 64 + 255) / 256, 256, 0, stream>>>(bufB, N * 64, scale, shift);

  // ---- layer 2 ----
  agg256<<<aggBlocks, 256, 0, stream>>>(bufB, offs, csr_src, csr_coef, dinv, bufA, N);
  gemm_kernel<<<gemmGrid, 256, 0, stream>>>(bufA, W2, bufB, N, 256);
  hipMemsetAsync(sums, 0, 512 * 4, stream);
  bn_stats<<<256, 256, 0, stream>>>(bufB, N, sums, sumsq);
  bn_finalize<<<1, 256, 0, stream>>>(sums, sumsq, gamma2, beta2, N, scale, shift);
  bn_apply<<<(N * 64 + 255) / 256, 256, 0, stream>>>(bufB, N * 64, scale, shift);

  // ---- pool + classifier ----
  hipMemsetAsync(pool, 0, (size_t)G * 256 * 4, stream);
  hipMemsetAsync(cnt, 0, G * 4, stream);
  cnt_kernel<<<(N + 255) / 256, 256, 0, stream>>>(batch, N, cnt);
  pool_kernel<<<G, 256, 0, stream>>>(bufB, batch, N, pool);
  final_kernel<<<G, 64, 0, stream>>>(pool, cnt, Wl, bl, out, NC);
}

// Round 2
// 849.853 us; speedup vs baseline: 1.4132x; 1.4132x over previous
//
#include <hip/hip_runtime.h>

#define BN_EPS 1e-5f

typedef __attribute__((ext_vector_type(8))) short bf16x8;
typedef __attribute__((ext_vector_type(4))) float f32x4;

__device__ __forceinline__ float bf2f(unsigned short u) {
  return __uint_as_float(((unsigned int)u) << 16);
}
__device__ __forceinline__ unsigned short f2bf(float f) {
  unsigned int u = __float_as_uint(f);
  u = u + 0x7FFFu + ((u >> 16) & 1u);   // round-to-nearest-even
  return (unsigned short)(u >> 16);
}

// ---------------- graph structure kernels ----------------

__global__ __launch_bounds__(256) void count_kernel(const int* __restrict__ dst, int E,
                                                    int* __restrict__ counts) {
  int e = blockIdx.x * 256 + threadIdx.x;
  if (e < E) atomicAdd(&counts[dst[e]], 1);
}

__global__ __launch_bounds__(256) void dinv_kernel(const int* __restrict__ counts, int N,
                                                   float* __restrict__ dinv) {
  int n = blockIdx.x * 256 + threadIdx.x;
  if (n < N) dinv[n] = rsqrtf((float)(counts[n] + 1));  // +1 self loop
}

__global__ __launch_bounds__(256) void scan1(const int* __restrict__ counts, int N,
                                             int* __restrict__ offs, int* __restrict__ blkSum) {
  __shared__ int sd[256];
  int t = threadIdx.x;
  int i0 = blockIdx.x * 1024 + t * 4;
  int v0 = (i0 + 0 < N) ? counts[i0 + 0] : 0;
  int v1 = (i0 + 1 < N) ? counts[i0 + 1] : 0;
  int v2 = (i0 + 2 < N) ? counts[i0 + 2] : 0;
  int v3 = (i0 + 3 < N) ? counts[i0 + 3] : 0;
  int tot = v0 + v1 + v2 + v3;
  sd[t] = tot;
  __syncthreads();
  for (int off = 1; off < 256; off <<= 1) {
    int x = (t >= off) ? sd[t - off] : 0;
    __syncthreads();
    sd[t] += x;
    __syncthreads();
  }
  int excl = sd[t] - tot;
  if (i0 + 0 < N) offs[i0 + 0] = excl;
  if (i0 + 1 < N) offs[i0 + 1] = excl + v0;
  if (i0 + 2 < N) offs[i0 + 2] = excl + v0 + v1;
  if (i0 + 3 < N) offs[i0 + 3] = excl + v0 + v1 + v2;
  if (t == 255) blkSum[blockIdx.x] = sd[255];
}

__global__ void scan2(const int* __restrict__ blkSum, int nb, int* __restrict__ blkOff,
                      int* __restrict__ offs, int N) {
  if (threadIdx.x == 0 && blockIdx.x == 0) {
    int run = 0;
    for (int b = 0; b < nb; ++b) { blkOff[b] = run; run += blkSum[b]; }
    offs[N] = run;
  }
}

__global__ __launch_bounds__(1024) void scan3(int* __restrict__ offs, int N,
                                              const int* __restrict__ blkOff) {
  int i = blockIdx.x * 1024 + threadIdx.x;
  if (i < N) offs[i] += blkOff[blockIdx.x];
}

__global__ __launch_bounds__(256) void fill_kernel(const int* __restrict__ src,
                                                   const int* __restrict__ dst, int E,
                                                   const int* __restrict__ offs,
                                                   int* __restrict__ cursor,
                                                   const float* __restrict__ dinv,
                                                   int* __restrict__ csr_src,
                                                   float* __restrict__ csr_coef) {
  int e = blockIdx.x * 256 + threadIdx.x;
  if (e >= E) return;
  int s = src[e], d = dst[e];
  int pos = offs[d] + atomicAdd(&cursor[d], 1);
  csr_src[pos]  = s;
  csr_coef[pos] = dinv[s] * dinv[d];
}

// ---------------- dtype conversion / weight transpose ----------------

__global__ __launch_bounds__(256) void cvt_x_kernel(const float* __restrict__ x,
                                                    unsigned short* __restrict__ xb, int total4) {
  int i = blockIdx.x * 256 + threadIdx.x;
  if (i >= total4) return;
  float4 v = ((const float4*)x)[i];
  unsigned int lo = (unsigned int)f2bf(v.x) | ((unsigned int)f2bf(v.y) << 16);
  unsigned int hi = (unsigned int)f2bf(v.z) | ((unsigned int)f2bf(v.w) << 16);
  ((uint2*)xb)[i] = make_uint2(lo, hi);
}

// W[K][256] (f32) -> Wt[256][K] (bf16)
__global__ __launch_bounds__(256) void cvtW_kernel(const float* __restrict__ W,
                                                   unsigned short* __restrict__ Wt, int K) {
  int idx = blockIdx.x * 256 + threadIdx.x;
  if (idx >= K * 256) return;
  int k = idx >> 8, n = idx & 255;
  Wt[n * K + k] = f2bf(W[k * 256 + n]);
}

// ---------------- aggregation (gather, CSR by dst), one wave per node ----------------
// 256-ch bf16 rows; optionally applies previous layer's BN scale/shift + ReLU on the fly.

template <bool APPLY>
__global__ __launch_bounds__(256) void agg256_bf(const unsigned short* __restrict__ h,
                                                 const int* __restrict__ offs,
                                                 const int* __restrict__ csr_src,
                                                 const float* __restrict__ csr_coef,
                                                 const float* __restrict__ dinv,
                                                 const float* __restrict__ scale,
                                                 const float* __restrict__ shift,
                                                 unsigned short* __restrict__ out, int N) {
  int n = (blockIdx.x * 256 + threadIdx.x) >> 6;
  int lane = threadIdx.x & 63;
  if (n >= N) return;
  int c0 = lane * 4;
  float4 sc = make_float4(1.f, 1.f, 1.f, 1.f), sh = make_float4(0.f, 0.f, 0.f, 0.f);
  if (APPLY) { sc = *(const float4*)&scale[c0]; sh = *(const float4*)&shift[c0]; }
  float di = dinv[n];
  float self = di * di;
  float ax, ay, az, aw;
  {
    uint2 v = *((const uint2*)(h + (size_t)n * 256) + lane);
    float fx = bf2f((unsigned short)(v.x & 0xffff));
    float fy = bf2f((unsigned short)(v.x >> 16));
    float fz = bf2f((unsigned short)(v.y & 0xffff));
    float fw = bf2f((unsigned short)(v.y >> 16));
    if (APPLY) {
      fx = fmaxf(fx * sc.x + sh.x, 0.f); fy = fmaxf(fy * sc.y + sh.y, 0.f);
      fz = fmaxf(fz * sc.z + sh.z, 0.f); fw = fmaxf(fw * sc.w + sh.w, 0.f);
    }
    ax = self * fx; ay = self * fy; az = self * fz; aw = self * fw;
  }
  int e0 = offs[n], e1 = offs[n + 1];
  for (int eb = e0; eb < e1; eb += 64) {
    int k = min(64, e1 - eb);
    int sv = 0; float cv = 0.f;
    if (lane < k) { sv = csr_src[eb + lane]; cv = csr_coef[eb + lane]; }
    for (int i = 0; i < k; ++i) {
      int s = __shfl(sv, i);
      float co = __shfl(cv, i);
      uint2 v = *((const uint2*)(h + (size_t)s * 256) + lane);
      float fx = bf2f((unsigned short)(v.x & 0xffff));
      float fy = bf2f((unsigned short)(v.x >> 16));
      float fz = bf2f((unsigned short)(v.y & 0xffff));
      float fw = bf2f((unsigned short)(v.y >> 16));
      if (APPLY) {
        fx = fmaxf(fx * sc.x + sh.x, 0.f); fy = fmaxf(fy * sc.y + sh.y, 0.f);
        fz = fmaxf(fz * sc.z + sh.z, 0.f); fw = fmaxf(fw * sc.w + sh.w, 0.f);
      }
      ax += co * fx; ay += co * fy; az += co * fz; aw += co * fw;
    }
  }
  unsigned int lo = (unsigned int)f2bf(ax) | ((unsigned int)f2bf(ay) << 16);
  unsigned int hi = (unsigned int)f2bf(az) | ((unsigned int)f2bf(aw) << 16);
  *((uint2*)(out + (size_t)n * 256) + lane) = make_uint2(lo, hi);
}

// 128-ch bf16 input (layer 0: raw x, no BN/ReLU)
__global__ __launch_bounds__(256) void agg128_bf(const unsigned short* __restrict__ h,
                                                 const int* __restrict__ offs,
                                                 const int* __restrict__ csr_src,
                                                 const float* __restrict__ csr_coef,
                                                 const float* __restrict__ dinv,
                                                 unsigned short* __restrict__ out, int N) {
  int n = (blockIdx.x * 256 + threadIdx.x) >> 6;
  int lane = threadIdx.x & 63;
  if (n >= N) return;
  float di = dinv[n];
  float self = di * di;
  float ax, ay;
  {
    unsigned int v = *((const unsigned int*)(h + (size_t)n * 128) + lane);
    ax = self * bf2f((unsigned short)(v & 0xffff));
    ay = self * bf2f((unsigned short)(v >> 16));
  }
  int e0 = offs[n], e1 = offs[n + 1];
  for (int eb = e0; eb < e1; eb += 64) {
    int k = min(64, e1 - eb);
    int sv = 0; float cv = 0.f;
    if (lane < k) { sv = csr_src[eb + lane]; cv = csr_coef[eb + lane]; }
    for (int i = 0; i < k; ++i) {
      int s = __shfl(sv, i);
      float co = __shfl(cv, i);
      unsigned int v = *((const unsigned int*)(h + (size_t)s * 128) + lane);
      ax += co * bf2f((unsigned short)(v & 0xffff));
      ay += co * bf2f((unsigned short)(v >> 16));
    }
  }
  *((unsigned int*)(out + (size_t)n * 128) + lane) =
      (unsigned int)f2bf(ax) | ((unsigned int)f2bf(ay) << 16);
}

// ---------------- bf16 MFMA GEMM: C[M,256] = A[M,K] @ W[K,256], Wt=[256][K] ----------------
// 128x64 tile, BK=64, 256 threads = 4 waves; wave w owns rows [32w,32w+32).

__global__ __launch_bounds__(256) void gemm_bf(const unsigned short* __restrict__ A,
                                               const unsigned short* __restrict__ Wt,
                                               unsigned short* __restrict__ C,
                                               int M, int K) {
  __shared__ unsigned short As[128][72];  // padded 64->72 (+16B) to break bank conflicts
  __shared__ unsigned short Bs[64][72];
  int t = threadIdx.x;
  int w = t >> 6, lane = t & 63;
  int l16 = lane & 15, lhi = lane >> 4;
  int rowBase = blockIdx.x * 128, colBase = blockIdx.y * 64;
  f32x4 acc[2][4] = {};
  int arow = t >> 1;            // 0..127
  int aoff = (t & 1) * 32;      // elements within BK
  int brow = t >> 2;            // 0..63
  int boff = (t & 3) * 16;
  const unsigned short* Abase = A + (size_t)(rowBase + arow) * K + aoff;
  const unsigned short* Bbase = Wt + (size_t)(colBase + brow) * K + boff;
  for (int k0 = 0; k0 < K; k0 += 64) {
    *(int4*)&As[arow][aoff]      = *(const int4*)(Abase + k0);
    *(int4*)&As[arow][aoff + 8]  = *(const int4*)(Abase + k0 + 8);
    *(int4*)&As[arow][aoff + 16] = *(const int4*)(Abase + k0 + 16);
    *(int4*)&As[arow][aoff + 24] = *(const int4*)(Abase + k0 + 24);
    *(int4*)&Bs[brow][boff]      = *(const int4*)(Bbase + k0);
    *(int4*)&Bs[brow][boff + 8]  = *(const int4*)(Bbase + k0 + 8);
    __syncthreads();
#pragma unroll
    for (int kk = 0; kk < 64; kk += 32) {
      bf16x8 a0 = *(const bf16x8*)&As[w * 32 + l16][kk + lhi * 8];
      bf16x8 a1 = *(const bf16x8*)&As[w * 32 + 16 + l16][kk + lhi * 8];
      bf16x8 b0 = *(const bf16x8*)&Bs[l16][kk + lhi * 8];
      bf16x8 b1 = *(const bf16x8*)&Bs[16 + l16][kk + lhi * 8];
      bf16x8 b2 = *(const bf16x8*)&Bs[32 + l16][kk + lhi * 8];
      bf16x8 b3 = *(const bf16x8*)&Bs[48 + l16][kk + lhi * 8];
      acc[0][0] = __builtin_amdgcn_mfma_f32_16x16x32_bf16(a0, b0, acc[0][0], 0, 0, 0);
      acc[0][1] = __builtin_amdgcn_mfma_f32_16x16x32_bf16(a0, b1, acc[0][1], 0, 0, 0);
      acc[0][2] = __builtin_amdgcn_mfma_f32_16x16x32_bf16(a0, b2, acc[0][2], 0, 0, 0);
      acc[0][3] = __builtin_amdgcn_mfma_f32_16x16x32_bf16(a0, b3, acc[0][3], 0, 0, 0);
      acc[1][0] = __builtin_amdgcn_mfma_f32_16x16x32_bf16(a1, b0, acc[1][0], 0, 0, 0);
      acc[1][1] = __builtin_amdgcn_mfma_f32_16x16x32_bf16(a1, b1, acc[1][1], 0, 0, 0);
      acc[1][2] = __builtin_amdgcn_mfma_f32_16x16x32_bf16(a1, b2, acc[1][2], 0, 0, 0);
      acc[1][3] = __builtin_amdgcn_mfma_f32_16x16x32_bf16(a1, b3, acc[1][3], 0, 0, 0);
    }
    __syncthreads();
  }
#pragma unroll
  for (int f = 0; f < 2; ++f) {
#pragma unroll
    for (int r = 0; r < 4; ++r) {
      int row = rowBase + w * 32 + f * 16 + lhi * 4 + r;
      if (row < M) {
        size_t o = (size_t)row * 256 + colBase + l16;
#pragma unroll
        for (int g = 0; g < 4; ++g) C[o + g * 16] = f2bf(acc[f][g][r]);
      }
    }
  }
}

// ---------------- batchnorm stats on bf16 h ----------------

__global__ __launch_bounds__(256) void bn_stats_bf(const unsigned short* __restrict__ h, int N,
                                                   float* __restrict__ sums,
                                                   float* __restrict__ sumsq) {
  int c = threadIdx.x;
  int rpb = (N + gridDim.x - 1) / gridDim.x;
  int r0 = blockIdx.x * rpb;
  int r1 = min(N, r0 + rpb);
  float s = 0.f, s2 = 0.f;
  for (int r = r0; r < r1; ++r) {
    float v = bf2f(h[(size_t)r * 256 + c]);
    s += v; s2 += v * v;
  }
  atomicAdd(&sums[c], s);
  atomicAdd(&sumsq[c], s2);
}

__global__ void bn_finalize(const float* __restrict__ sums, const float* __restrict__ sumsq,
                            const float* __restrict__ gamma, const float* __restrict__ beta,
                            int N, float* __restrict__ scale, float* __restrict__ shift) {
  int c = threadIdx.x;  // 256
  float inv_n = 1.0f / (float)N;
  float mean = sums[c] * inv_n;
  float var = sumsq[c] * inv_n - mean * mean;
  float sc = gamma[c] * rsqrtf(var + BN_EPS);
  scale[c] = sc;
  shift[c] = beta[c] - mean * sc;
}

// ---------------- pooling (fused BN+ReLU) + classifier ----------------

__global__ __launch_bounds__(256) void cnt_kernel(const int* __restrict__ batch, int N,
                                                  int* __restrict__ cnt) {
  int i = blockIdx.x * 256 + threadIdx.x;
  if (i < N) atomicAdd(&cnt[batch[i]], 1);
}

__global__ __launch_bounds__(256) void pool_bf(const unsigned short* __restrict__ h,
                                               const int* __restrict__ batch, int N,
                                               const float* __restrict__ scale,
                                               const float* __restrict__ shift,
                                               float* __restrict__ pool) {
  int c = threadIdx.x;
  float sc = scale[c], sh = shift[c];
  int rpb = (N + gridDim.x - 1) / gridDim.x;
  int r0 = blockIdx.x * rpb;
  int r1 = min(N, r0 + rpb);
  if (r0 >= r1) return;
  float acc = 0.f;
  int cur = batch[r0];
  for (int r = r0; r < r1; ++r) {
    int g = batch[r];
    if (g != cur) { atomicAdd(&pool[(size_t)cur * 256 + c], acc); acc = 0.f; cur = g; }
    acc += fmaxf(bf2f(h[(size_t)r * 256 + c]) * sc + sh, 0.f);
  }
  atomicAdd(&pool[(size_t)cur * 256 + c], acc);
}

__global__ __launch_bounds__(64) void final_kernel(const float* __restrict__ pool,
                                                   const int* __restrict__ cnt,
                                                   const float* __restrict__ Wl,
                                                   const float* __restrict__ bl,
                                                   float* __restrict__ out, int NC) {
  __shared__ float p[256];
  int g = blockIdx.x, t = threadIdx.x;
  float inv = 1.0f / fmaxf((float)cnt[g], 1.0f);
  for (int i = t; i < 256; i += 64) p[i] = pool[(size_t)g * 256 + i] * inv;
  __syncthreads();
  if (t < NC) {
    float s = bl[t];
    for (int k = 0; k < 256; ++k) s += p[k] * Wl[k * NC + t];
    out[g * NC + t] = s;
  }
}

// ---------------- launcher ----------------

extern "C" void kernel_launch(void* const* d_in, const int* in_sizes, int n_in,
                              void* d_out, int out_size, void* d_ws, size_t ws_size,
                              hipStream_t stream) {
  const float* x      = (const float*)d_in[0];
  const int*   ei     = (const int*)d_in[1];
  const int*   batch  = (const int*)d_in[2];
  const float* W0     = (const float*)d_in[3];
  const float* gamma0 = (const float*)d_in[5];
  const float* beta0  = (const float*)d_in[6];
  const float* W1     = (const float*)d_in[7];
  const float* gamma1 = (const float*)d_in[9];
  const float* beta1  = (const float*)d_in[10];
  const float* W2     = (const float*)d_in[11];
  const float* gamma2 = (const float*)d_in[13];
  const float* beta2  = (const float*)d_in[14];
  const float* Wl     = (const float*)d_in[15];
  const float* bl     = (const float*)d_in[16];
  float* out = (float*)d_out;

  int N = in_sizes[0] / 128;  // 50000
  int E = in_sizes[1] / 2;    // 800000
  int G = 128;
  int NC = 40;
  const int* src = ei;
  const int* dst = ei + E;

  char* p = (char*)d_ws;
  auto alloc = [&](size_t bytes) -> void* {
    void* r = (void*)p;
    p += (bytes + 255) & ~(size_t)255;
    return r;
  };
  unsigned short* xb  = (unsigned short*)alloc((size_t)N * 128 * 2);
  unsigned short* hA  = (unsigned short*)alloc((size_t)N * 256 * 2);  // agg out / gemm in
  unsigned short* hB  = (unsigned short*)alloc((size_t)N * 256 * 2);  // gemm out (h_raw)
  unsigned short* Wt0 = (unsigned short*)alloc((size_t)256 * 128 * 2);
  unsigned short* Wt1 = (unsigned short*)alloc((size_t)256 * 256 * 2);
  unsigned short* Wt2 = (unsigned short*)alloc((size_t)256 * 256 * 2);
  int*   csr_src  = (int*)  alloc((size_t)E * 4);
  float* csr_coef = (float*)alloc((size_t)E * 4);
  int*   counts   = (int*)  alloc((size_t)N * 4);
  int*   cursor   = (int*)  alloc((size_t)N * 4);
  int*   offs     = (int*)  alloc((size_t)(N + 1) * 4);
  float* dinv     = (float*)alloc((size_t)N * 4);
  int*   blkSum   = (int*)  alloc(64 * 4);
  int*   blkOff   = (int*)  alloc(64 * 4);
  float* sums     = (float*)alloc(512 * 4);
  float* sumsq    = sums + 256;
  float* scale0   = (float*)alloc(256 * 4);
  float* shift0   = (float*)alloc(256 * 4);
  float* scale1   = (float*)alloc(256 * 4);
  float* shift1   = (float*)alloc(256 * 4);
  float* scale2   = (float*)alloc(256 * 4);
  float* shift2   = (float*)alloc(256 * 4);
  float* pool     = (float*)alloc((size_t)G * 256 * 4);
  int*   cnt      = (int*)  alloc(G * 4);

  // ---- graph structure (once per launch) ----
  hipMemsetAsync(counts, 0, (size_t)N * 4, stream);
  hipMemsetAsync(cursor, 0, (size_t)N * 4, stream);
  count_kernel<<<(E + 255) / 256, 256, 0, stream>>>(dst, E, counts);
  dinv_kernel<<<(N + 255) / 256, 256, 0, stream>>>(counts, N, dinv);
  int nb = (N + 1023) / 1024;
  scan1<<<nb, 256, 0, stream>>>(counts, N, offs, blkSum);
  scan2<<<1, 1, 0, stream>>>(blkSum, nb, blkOff, offs, N);
  scan3<<<nb, 1024, 0, stream>>>(offs, N, blkOff);
  fill_kernel<<<(E + 255) / 256, 256, 0, stream>>>(src, dst, E, offs, cursor, dinv,
                                                   csr_src, csr_coef);

  // ---- dtype prep ----
  cvt_x_kernel<<<(N * 128 / 4 + 255) / 256, 256, 0, stream>>>(x, xb, N * 128 / 4);
  cvtW_kernel<<<(128 * 256 + 255) / 256, 256, 0, stream>>>(W0, Wt0, 128);
  cvtW_kernel<<<(256 * 256 + 255) / 256, 256, 0, stream>>>(W1, Wt1, 256);
  cvtW_kernel<<<(256 * 256 + 255) / 256, 256, 0, stream>>>(W2, Wt2, 256);

  int aggBlocks = (N + 3) / 4;
  dim3 gemmGrid((N + 127) / 128, 4);

  // ---- layer 0 (x: 128 ch, no preceding BN). conv bias cancels under BN. ----
  agg128_bf<<<aggBlocks, 256, 0, stream>>>(xb, offs, csr_src, csr_coef, dinv, hA, N);
  gemm_bf<<<gemmGrid, 256, 0, stream>>>(hA, Wt0, hB, N, 128);
  hipMemsetAsync(sums, 0, 512 * 4, stream);
  bn_stats_bf<<<256, 256, 0, stream>>>(hB, N, sums, sumsq);
  bn_finalize<<<1, 256, 0, stream>>>(sums, sumsq, gamma0, beta0, N, scale0, shift0);

  // ---- layer 1 (BN0+ReLU applied on the fly during gather) ----
  agg256_bf<true><<<aggBlocks, 256, 0, stream>>>(hB, offs, csr_src, csr_coef, dinv,
                                                 scale0, shift0, hA, N);
  gemm_bf<<<gemmGrid, 256, 0, stream>>>(hA, Wt1, hB, N, 256);
  hipMemsetAsync(sums, 0, 512 * 4, stream);
  bn_stats_bf<<<256, 256, 0, stream>>>(hB, N, sums, sumsq);
  bn_finalize<<<1, 256, 0, stream>>>(sums, sumsq, gamma1, beta1, N, scale1, shift1);

  // ---- layer 2 ----
  agg256_bf<true><<<aggBlocks, 256, 0, stream>>>(hB, offs, csr_src, csr_coef, dinv,
                                                 scale1, shift1, hA, N);
  gemm_bf<<<gemmGrid, 256, 0, stream>>>(hA, Wt2, hB, N, 256);
  hipMemsetAsync(sums, 0, 512 * 4, stream);
  bn_stats_bf<<<256, 256, 0, stream>>>(hB, N, sums, sumsq);
  bn_finalize<<<1, 256, 0, stream>>>(sums, sumsq, gamma2, beta2, N, scale2, shift2);

  // ---- pool (BN2+ReLU fused) + classifier ----
  hipMemsetAsync(pool, 0, (size_t)G * 256 * 4, stream);
  hipMemsetAsync(cnt, 0, G * 4, stream);
  cnt_kernel<<<(N + 255) / 256, 256, 0, stream>>>(batch, N, cnt);
  pool_bf<<<G, 256, 0, stream>>>(hB, batch, N, scale2, shift2, pool);
  final_kernel<<<G, 64, 0, stream>>>(pool, cnt, Wl, bl, out, NC);
}

// Round 3
// 660.462 us; speedup vs baseline: 1.8184x; 1.2868x over previous
//
#include <hip/hip_runtime.h>

#define BN_EPS 1e-5f

typedef __attribute__((ext_vector_type(8))) short bf16x8;
typedef __attribute__((ext_vector_type(4))) float f32x4;

__device__ __forceinline__ float bf2f(unsigned short u) {
  return __uint_as_float(((unsigned int)u) << 16);
}
__device__ __forceinline__ unsigned short f2bf(float f) {
  unsigned int u = __float_as_uint(f);
  u = u + 0x7FFFu + ((u >> 16) & 1u);   // round-to-nearest-even
  return (unsigned short)(u >> 16);
}

// ---------------- graph structure kernels ----------------

__global__ __launch_bounds__(256) void count_kernel(const int* __restrict__ dst, int E,
                                                    int* __restrict__ counts) {
  int e = blockIdx.x * 256 + threadIdx.x;
  if (e < E) atomicAdd(&counts[dst[e]], 1);
}

__global__ __launch_bounds__(256) void dinv_kernel(const int* __restrict__ counts, int N,
                                                   float* __restrict__ dinv) {
  int n = blockIdx.x * 256 + threadIdx.x;
  if (n < N) dinv[n] = rsqrtf((float)(counts[n] + 1));  // +1 self loop
}

__global__ __launch_bounds__(256) void scan1(const int* __restrict__ counts, int N,
                                             int* __restrict__ offs, int* __restrict__ blkSum) {
  __shared__ int sd[256];
  int t = threadIdx.x;
  int i0 = blockIdx.x * 1024 + t * 4;
  int v0 = (i0 + 0 < N) ? counts[i0 + 0] : 0;
  int v1 = (i0 + 1 < N) ? counts[i0 + 1] : 0;
  int v2 = (i0 + 2 < N) ? counts[i0 + 2] : 0;
  int v3 = (i0 + 3 < N) ? counts[i0 + 3] : 0;
  int tot = v0 + v1 + v2 + v3;
  sd[t] = tot;
  __syncthreads();
  for (int off = 1; off < 256; off <<= 1) {
    int x = (t >= off) ? sd[t - off] : 0;
    __syncthreads();
    sd[t] += x;
    __syncthreads();
  }
  int excl = sd[t] - tot;
  if (i0 + 0 < N) offs[i0 + 0] = excl;
  if (i0 + 1 < N) offs[i0 + 1] = excl + v0;
  if (i0 + 2 < N) offs[i0 + 2] = excl + v0 + v1;
  if (i0 + 3 < N) offs[i0 + 3] = excl + v0 + v1 + v2;
  if (t == 255) blkSum[blockIdx.x] = sd[255];
}

__global__ void scan2(const int* __restrict__ blkSum, int nb, int* __restrict__ blkOff,
                      int* __restrict__ offs, int N) {
  if (threadIdx.x == 0 && blockIdx.x == 0) {
    int run = 0;
    for (int b = 0; b < nb; ++b) { blkOff[b] = run; run += blkSum[b]; }
    offs[N] = run;
  }
}

__global__ __launch_bounds__(1024) void scan3(int* __restrict__ offs, int N,
                                              const int* __restrict__ blkOff) {
  int i = blockIdx.x * 1024 + threadIdx.x;
  if (i < N) offs[i] += blkOff[blockIdx.x];
}

__global__ __launch_bounds__(256) void fill_kernel(const int* __restrict__ src,
                                                   const int* __restrict__ dst, int E,
                                                   const int* __restrict__ offs,
                                                   int* __restrict__ cursor,
                                                   const float* __restrict__ dinv,
                                                   int* __restrict__ csr_src,
                                                   float* __restrict__ csr_coef) {
  int e = blockIdx.x * 256 + threadIdx.x;
  if (e >= E) return;
  int s = src[e], d = dst[e];
  int pos = offs[d] + atomicAdd(&cursor[d], 1);
  csr_src[pos]  = s;
  csr_coef[pos] = dinv[s] * dinv[d];
}

// ---------------- graph-id boundaries (batch is sorted; ~128 atomics total) ----------------

__global__ __launch_bounds__(256) void boundary_kernel(const int* __restrict__ batch, int N,
                                                       unsigned int* __restrict__ gstart) {
  int i = blockIdx.x * 256 + threadIdx.x;
  if (i >= N) return;
  if (i == 0 || batch[i] != batch[i - 1]) atomicMin(&gstart[batch[i]], (unsigned int)i);
}

__global__ void fixup_kernel(unsigned int* __restrict__ gstart, int N, int G) {
  if (threadIdx.x == 0 && blockIdx.x == 0) {
    gstart[G] = (unsigned int)N;
    for (int g = G - 1; g >= 0; --g)
      if (gstart[g] == 0xFFFFFFFFu) gstart[g] = gstart[g + 1];
  }
}

// ---------------- dtype conversion / weight transpose ----------------

__global__ __launch_bounds__(256) void cvt_x_kernel(const float* __restrict__ x,
                                                    unsigned short* __restrict__ xb, int total4) {
  int i = blockIdx.x * 256 + threadIdx.x;
  if (i >= total4) return;
  float4 v = ((const float4*)x)[i];
  unsigned int lo = (unsigned int)f2bf(v.x) | ((unsigned int)f2bf(v.y) << 16);
  unsigned int hi = (unsigned int)f2bf(v.z) | ((unsigned int)f2bf(v.w) << 16);
  ((uint2*)xb)[i] = make_uint2(lo, hi);
}

// W[K][256] (f32) -> Wt[256][K] (bf16)
__global__ __launch_bounds__(256) void cvtW_kernel(const float* __restrict__ W,
                                                   unsigned short* __restrict__ Wt, int K) {
  int idx = blockIdx.x * 256 + threadIdx.x;
  if (idx >= K * 256) return;
  int k = idx >> 8, n = idx & 255;
  Wt[n * K + k] = f2bf(W[k * 256 + n]);
}

// ---------------- aggregation (gather, CSR by dst), one wave per node ----------------

template <bool APPLY>
__global__ __launch_bounds__(256) void agg256_bf(const unsigned short* __restrict__ h,
                                                 const int* __restrict__ offs,
                                                 const int* __restrict__ csr_src,
                                                 const float* __restrict__ csr_coef,
                                                 const float* __restrict__ dinv,
                                                 const float* __restrict__ scale,
                                                 const float* __restrict__ shift,
                                                 unsigned short* __restrict__ out, int N) {
  int n = (blockIdx.x * 256 + threadIdx.x) >> 6;
  int lane = threadIdx.x & 63;
  if (n >= N) return;
  int c0 = lane * 4;
  float4 sc = make_float4(1.f, 1.f, 1.f, 1.f), sh = make_float4(0.f, 0.f, 0.f, 0.f);
  if (APPLY) { sc = *(const float4*)&scale[c0]; sh = *(const float4*)&shift[c0]; }
  float di = dinv[n];
  float self = di * di;
  float ax, ay, az, aw;
  {
    uint2 v = *((const uint2*)(h + (size_t)n * 256) + lane);
    float fx = bf2f((unsigned short)(v.x & 0xffff));
    float fy = bf2f((unsigned short)(v.x >> 16));
    float fz = bf2f((unsigned short)(v.y & 0xffff));
    float fw = bf2f((unsigned short)(v.y >> 16));
    if (APPLY) {
      fx = fmaxf(fx * sc.x + sh.x, 0.f); fy = fmaxf(fy * sc.y + sh.y, 0.f);
      fz = fmaxf(fz * sc.z + sh.z, 0.f); fw = fmaxf(fw * sc.w + sh.w, 0.f);
    }
    ax = self * fx; ay = self * fy; az = self * fz; aw = self * fw;
  }
  int e0 = offs[n], e1 = offs[n + 1];
  for (int eb = e0; eb < e1; eb += 64) {
    int k = min(64, e1 - eb);
    int sv = 0; float cv = 0.f;
    if (lane < k) { sv = csr_src[eb + lane]; cv = csr_coef[eb + lane]; }
    for (int i = 0; i < k; ++i) {
      int s = __shfl(sv, i);
      float co = __shfl(cv, i);
      uint2 v = *((const uint2*)(h + (size_t)s * 256) + lane);
      float fx = bf2f((unsigned short)(v.x & 0xffff));
      float fy = bf2f((unsigned short)(v.x >> 16));
      float fz = bf2f((unsigned short)(v.y & 0xffff));
      float fw = bf2f((unsigned short)(v.y >> 16));
      if (APPLY) {
        fx = fmaxf(fx * sc.x + sh.x, 0.f); fy = fmaxf(fy * sc.y + sh.y, 0.f);
        fz = fmaxf(fz * sc.z + sh.z, 0.f); fw = fmaxf(fw * sc.w + sh.w, 0.f);
      }
      ax += co * fx; ay += co * fy; az += co * fz; aw += co * fw;
    }
  }
  unsigned int lo = (unsigned int)f2bf(ax) | ((unsigned int)f2bf(ay) << 16);
  unsigned int hi = (unsigned int)f2bf(az) | ((unsigned int)f2bf(aw) << 16);
  *((uint2*)(out + (size_t)n * 256) + lane) = make_uint2(lo, hi);
}

__global__ __launch_bounds__(256) void agg128_bf(const unsigned short* __restrict__ h,
                                                 const int* __restrict__ offs,
                                                 const int* __restrict__ csr_src,
                                                 const float* __restrict__ csr_coef,
                                                 const float* __restrict__ dinv,
                                                 unsigned short* __restrict__ out, int N) {
  int n = (blockIdx.x * 256 + threadIdx.x) >> 6;
  int lane = threadIdx.x & 63;
  if (n >= N) return;
  float di = dinv[n];
  float self = di * di;
  float ax, ay;
  {
    unsigned int v = *((const unsigned int*)(h + (size_t)n * 128) + lane);
    ax = self * bf2f((unsigned short)(v & 0xffff));
    ay = self * bf2f((unsigned short)(v >> 16));
  }
  int e0 = offs[n], e1 = offs[n + 1];
  for (int eb = e0; eb < e1; eb += 64) {
    int k = min(64, e1 - eb);
    int sv = 0; float cv = 0.f;
    if (lane < k) { sv = csr_src[eb + lane]; cv = csr_coef[eb + lane]; }
    for (int i = 0; i < k; ++i) {
      int s = __shfl(sv, i);
      float co = __shfl(cv, i);
      unsigned int v = *((const unsigned int*)(h + (size_t)s * 128) + lane);
      ax += co * bf2f((unsigned short)(v & 0xffff));
      ay += co * bf2f((unsigned short)(v >> 16));
    }
  }
  *((unsigned int*)(out + (size_t)n * 128) + lane) =
      (unsigned int)f2bf(ax) | ((unsigned int)f2bf(ay) << 16);
}

// ---------------- bf16 MFMA GEMM: C[M,256] = A[M,K] @ W[K,256], Wt=[256][K] ----------------

__global__ __launch_bounds__(256) void gemm_bf(const unsigned short* __restrict__ A,
                                               const unsigned short* __restrict__ Wt,
                                               unsigned short* __restrict__ C,
                                               int M, int K) {
  __shared__ unsigned short As[128][72];
  __shared__ unsigned short Bs[64][72];
  int t = threadIdx.x;
  int w = t >> 6, lane = t & 63;
  int l16 = lane & 15, lhi = lane >> 4;
  int rowBase = blockIdx.x * 128, colBase = blockIdx.y * 64;
  f32x4 acc[2][4] = {};
  int arow = t >> 1;
  int aoff = (t & 1) * 32;
  int brow = t >> 2;
  int boff = (t & 3) * 16;
  const unsigned short* Abase = A + (size_t)(rowBase + arow) * K + aoff;
  const unsigned short* Bbase = Wt + (size_t)(colBase + brow) * K + boff;
  for (int k0 = 0; k0 < K; k0 += 64) {
    *(int4*)&As[arow][aoff]      = *(const int4*)(Abase + k0);
    *(int4*)&As[arow][aoff + 8]  = *(const int4*)(Abase + k0 + 8);
    *(int4*)&As[arow][aoff + 16] = *(const int4*)(Abase + k0 + 16);
    *(int4*)&As[arow][aoff + 24] = *(const int4*)(Abase + k0 + 24);
    *(int4*)&Bs[brow][boff]      = *(const int4*)(Bbase + k0);
    *(int4*)&Bs[brow][boff + 8]  = *(const int4*)(Bbase + k0 + 8);
    __syncthreads();
#pragma unroll
    for (int kk = 0; kk < 64; kk += 32) {
      bf16x8 a0 = *(const bf16x8*)&As[w * 32 + l16][kk + lhi * 8];
      bf16x8 a1 = *(const bf16x8*)&As[w * 32 + 16 + l16][kk + lhi * 8];
      bf16x8 b0 = *(const bf16x8*)&Bs[l16][kk + lhi * 8];
      bf16x8 b1 = *(const bf16x8*)&Bs[16 + l16][kk + lhi * 8];
      bf16x8 b2 = *(const bf16x8*)&Bs[32 + l16][kk + lhi * 8];
      bf16x8 b3 = *(const bf16x8*)&Bs[48 + l16][kk + lhi * 8];
      acc[0][0] = __builtin_amdgcn_mfma_f32_16x16x32_bf16(a0, b0, acc[0][0], 0, 0, 0);
      acc[0][1] = __builtin_amdgcn_mfma_f32_16x16x32_bf16(a0, b1, acc[0][1], 0, 0, 0);
      acc[0][2] = __builtin_amdgcn_mfma_f32_16x16x32_bf16(a0, b2, acc[0][2], 0, 0, 0);
      acc[0][3] = __builtin_amdgcn_mfma_f32_16x16x32_bf16(a0, b3, acc[0][3], 0, 0, 0);
      acc[1][0] = __builtin_amdgcn_mfma_f32_16x16x32_bf16(a1, b0, acc[1][0], 0, 0, 0);
      acc[1][1] = __builtin_amdgcn_mfma_f32_16x16x32_bf16(a1, b1, acc[1][1], 0, 0, 0);
      acc[1][2] = __builtin_amdgcn_mfma_f32_16x16x32_bf16(a1, b2, acc[1][2], 0, 0, 0);
      acc[1][3] = __builtin_amdgcn_mfma_f32_16x16x32_bf16(a1, b3, acc[1][3], 0, 0, 0);
    }
    __syncthreads();
  }
#pragma unroll
  for (int f = 0; f < 2; ++f) {
#pragma unroll
    for (int r = 0; r < 4; ++r) {
      int row = rowBase + w * 32 + f * 16 + lhi * 4 + r;
      if (row < M) {
        size_t o = (size_t)row * 256 + colBase + l16;
#pragma unroll
        for (int g = 0; g < 4; ++g) C[o + g * 16] = f2bf(acc[f][g][r]);
      }
    }
  }
}

// ---------------- batchnorm ----------------

__global__ __launch_bounds__(256) void bn_stats_bf(const unsigned short* __restrict__ h, int N,
                                                   float* __restrict__ sums,
                                                   float* __restrict__ sumsq) {
  int c = threadIdx.x;
  int rpb = (N + gridDim.x - 1) / gridDim.x;
  int r0 = blockIdx.x * rpb;
  int r1 = min(N, r0 + rpb);
  float s = 0.f, s2 = 0.f;
  for (int r = r0; r < r1; ++r) {
    float v = bf2f(h[(size_t)r * 256 + c]);
    s += v; s2 += v * v;
  }
  atomicAdd(&sums[c], s);
  atomicAdd(&sumsq[c], s2);
}

__global__ void bn_finalize(const float* __restrict__ sums, const float* __restrict__ sumsq,
                            const float* __restrict__ gamma, const float* __restrict__ beta,
                            int N, float* __restrict__ scale, float* __restrict__ shift) {
  int c = threadIdx.x;  // 256
  float inv_n = 1.0f / (float)N;
  float mean = sums[c] * inv_n;
  float var = sumsq[c] * inv_n - mean * mean;
  float sc = gamma[c] * rsqrtf(var + BN_EPS);
  scale[c] = sc;
  shift[c] = beta[c] - mean * sc;
}

// ---------------- pooling (BN+ReLU fused, partials, no atomics) + classifier ----------------

#define PSLICES 8

__global__ __launch_bounds__(256) void pool_part_bf(const unsigned short* __restrict__ h,
                                                    const unsigned int* __restrict__ gstart,
                                                    const float* __restrict__ scale,
                                                    const float* __restrict__ shift,
                                                    float* __restrict__ pool_part) {
  int g = blockIdx.x >> 3, s = blockIdx.x & (PSLICES - 1);
  int c = threadIdx.x;
  int gs = (int)gstart[g], ge = (int)gstart[g + 1];
  int len = ge - gs;
  int r0 = gs + (int)(((long long)len * s) / PSLICES);
  int r1 = gs + (int)(((long long)len * (s + 1)) / PSLICES);
  float sc = scale[c], sh = shift[c];
  float acc = 0.f;
  for (int r = r0; r < r1; ++r)
    acc += fmaxf(bf2f(h[(size_t)r * 256 + c]) * sc + sh, 0.f);
  pool_part[(size_t)blockIdx.x * 256 + c] = acc;
}

__global__ __launch_bounds__(64) void final_kernel(const float* __restrict__ pool_part,
                                                   const unsigned int* __restrict__ gstart,
                                                   const float* __restrict__ Wl,
                                                   const float* __restrict__ bl,
                                                   float* __restrict__ out, int NC) {
  __shared__ float p[256];
  int g = blockIdx.x, t = threadIdx.x;
  float len = (float)((int)gstart[g + 1] - (int)gstart[g]);
  float inv = 1.0f / fmaxf(len, 1.0f);
  for (int i = t; i < 256; i += 64) {
    float s = 0.f;
#pragma unroll
    for (int k = 0; k < PSLICES; ++k) s += pool_part[(size_t)(g * PSLICES + k) * 256 + i];
    p[i] = s * inv;
  }
  __syncthreads();
  if (t < NC) {
    float s = bl[t];
    for (int k = 0; k < 256; ++k) s += p[k] * Wl[k * NC + t];
    out[g * NC + t] = s;
  }
}

// ---------------- launcher ----------------

extern "C" void kernel_launch(void* const* d_in, const int* in_sizes, int n_in,
                              void* d_out, int out_size, void* d_ws, size_t ws_size,
                              hipStream_t stream) {
  const float* x      = (const float*)d_in[0];
  const int*   ei     = (const int*)d_in[1];
  const int*   batch  = (const int*)d_in[2];
  const float* W0     = (const float*)d_in[3];
  const float* gamma0 = (const float*)d_in[5];
  const float* beta0  = (const float*)d_in[6];
  const float* W1     = (const float*)d_in[7];
  const float* gamma1 = (const float*)d_in[9];
  const float* beta1  = (const float*)d_in[10];
  const float* W2     = (const float*)d_in[11];
  const float* gamma2 = (const float*)d_in[13];
  const float* beta2  = (const float*)d_in[14];
  const float* Wl     = (const float*)d_in[15];
  const float* bl     = (const float*)d_in[16];
  float* out = (float*)d_out;

  int N = in_sizes[0] / 128;  // 50000
  int E = in_sizes[1] / 2;    // 800000
  int G = 128;
  int NC = 40;
  const int* src = ei;
  const int* dst = ei + E;

  char* p = (char*)d_ws;
  auto alloc = [&](size_t bytes) -> void* {
    void* r = (void*)p;
    p += (bytes + 255) & ~(size_t)255;
    return r;
  };
  unsigned short* xb  = (unsigned short*)alloc((size_t)N * 128 * 2);
  unsigned short* hA  = (unsigned short*)alloc((size_t)N * 256 * 2);
  unsigned short* hB  = (unsigned short*)alloc((size_t)N * 256 * 2);
  unsigned short* Wt0 = (unsigned short*)alloc((size_t)256 * 128 * 2);
  unsigned short* Wt1 = (unsigned short*)alloc((size_t)256 * 256 * 2);
  unsigned short* Wt2 = (unsigned short*)alloc((size_t)256 * 256 * 2);
  int*   csr_src  = (int*)  alloc((size_t)E * 4);
  float* csr_coef = (float*)alloc((size_t)E * 4);
  int*   counts   = (int*)  alloc((size_t)N * 4);
  int*   cursor   = (int*)  alloc((size_t)N * 4);
  int*   offs     = (int*)  alloc((size_t)(N + 1) * 4);
  float* dinv     = (float*)alloc((size_t)N * 4);
  int*   blkSum   = (int*)  alloc(64 * 4);
  int*   blkOff   = (int*)  alloc(64 * 4);
  float* sums     = (float*)alloc(512 * 4);
  float* sumsq    = sums + 256;
  float* scale0   = (float*)alloc(256 * 4);
  float* shift0   = (float*)alloc(256 * 4);
  float* scale1   = (float*)alloc(256 * 4);
  float* shift1   = (float*)alloc(256 * 4);
  float* scale2   = (float*)alloc(256 * 4);
  float* shift2   = (float*)alloc(256 * 4);
  unsigned int* gstart = (unsigned int*)alloc((size_t)(G + 1) * 4);
  float* pool_part = (float*)alloc((size_t)G * PSLICES * 256 * 4);

  // ---- graph structure (once per launch) ----
  hipMemsetAsync(counts, 0, (size_t)N * 4, stream);
  hipMemsetAsync(cursor, 0, (size_t)N * 4, stream);
  hipMemsetAsync(gstart, 0xFF, (size_t)(G + 1) * 4, stream);
  count_kernel<<<(E + 255) / 256, 256, 0, stream>>>(dst, E, counts);
  dinv_kernel<<<(N + 255) / 256, 256, 0, stream>>>(counts, N, dinv);
  int nb = (N + 1023) / 1024;
  scan1<<<nb, 256, 0, stream>>>(counts, N, offs, blkSum);
  scan2<<<1, 1, 0, stream>>>(blkSum, nb, blkOff, offs, N);
  scan3<<<nb, 1024, 0, stream>>>(offs, N, blkOff);
  fill_kernel<<<(E + 255) / 256, 256, 0, stream>>>(src, dst, E, offs, cursor, dinv,
                                                   csr_src, csr_coef);
  boundary_kernel<<<(N + 255) / 256, 256, 0, stream>>>(batch, N, gstart);
  fixup_kernel<<<1, 1, 0, stream>>>(gstart, N, G);

  // ---- dtype prep ----
  cvt_x_kernel<<<(N * 128 / 4 + 255) / 256, 256, 0, stream>>>(x, xb, N * 128 / 4);
  cvtW_kernel<<<(128 * 256 + 255) / 256, 256, 0, stream>>>(W0, Wt0, 128);
  cvtW_kernel<<<(256 * 256 + 255) / 256, 256, 0, stream>>>(W1, Wt1, 256);
  cvtW_kernel<<<(256 * 256 + 255) / 256, 256, 0, stream>>>(W2, Wt2, 256);

  int aggBlocks = (N + 3) / 4;
  dim3 gemmGrid((N + 127) / 128, 4);

  // ---- layer 0 ----
  agg128_bf<<<aggBlocks, 256, 0, stream>>>(xb, offs, csr_src, csr_coef, dinv, hA, N);
  gemm_bf<<<gemmGrid, 256, 0, stream>>>(hA, Wt0, hB, N, 128);
  hipMemsetAsync(sums, 0, 512 * 4, stream);
  bn_stats_bf<<<256, 256, 0, stream>>>(hB, N, sums, sumsq);
  bn_finalize<<<1, 256, 0, stream>>>(sums, sumsq, gamma0, beta0, N, scale0, shift0);

  // ---- layer 1 ----
  agg256_bf<true><<<aggBlocks, 256, 0, stream>>>(hB, offs, csr_src, csr_coef, dinv,
                                                 scale0, shift0, hA, N);
  gemm_bf<<<gemmGrid, 256, 0, stream>>>(hA, Wt1, hB, N, 256);
  hipMemsetAsync(sums, 0, 512 * 4, stream);
  bn_stats_bf<<<256, 256, 0, stream>>>(hB, N, sums, sumsq);
  bn_finalize<<<1, 256, 0, stream>>>(sums, sumsq, gamma1, beta1, N, scale1, shift1);

  // ---- layer 2 ----
  agg256_bf<true><<<aggBlocks, 256, 0, stream>>>(hB, offs, csr_src, csr_coef, dinv,
                                                 scale1, shift1, hA, N);
  gemm_bf<<<gemmGrid, 256, 0, stream>>>(hA, Wt2, hB, N, 256);
  hipMemsetAsync(sums, 0, 512 * 4, stream);
  bn_stats_bf<<<256, 256, 0, stream>>>(hB, N, sums, sumsq);
  bn_finalize<<<1, 256, 0, stream>>>(sums, sumsq, gamma2, beta2, N, scale2, shift2);

  // ---- pool + classifier ----
  pool_part_bf<<<G * PSLICES, 256, 0, stream>>>(hB, gstart, scale2, shift2, pool_part);
  final_kernel<<<G, 64, 0, stream>>>(pool_part, gstart, Wl, bl, out, NC);
}

// Round 4
// 601.877 us; speedup vs baseline: 1.9954x; 1.0973x over previous
//
#include <hip/hip_runtime.h>

#define BN_EPS 1e-5f

typedef __attribute__((ext_vector_type(8))) short bf16x8;
typedef __attribute__((ext_vector_type(4))) float f32x4;

__device__ __forceinline__ float bf2f(unsigned short u) {
  return __uint_as_float(((unsigned int)u) << 16);
}
__device__ __forceinline__ unsigned short f2bf(float f) {
  unsigned int u = __float_as_uint(f);
  u = u + 0x7FFFu + ((u >> 16) & 1u);   // round-to-nearest-even
  return (unsigned short)(u >> 16);
}

// ---------------- graph structure kernels ----------------

__global__ __launch_bounds__(256) void count_kernel(const int* __restrict__ dst, int E,
                                                    int* __restrict__ counts) {
  int e = blockIdx.x * 256 + threadIdx.x;
  if (e < E) atomicAdd(&counts[dst[e]], 1);
}

// scan1 also produces dinv = rsqrt(deg+1) in the same pass over counts
__global__ __launch_bounds__(256) void scan1(const int* __restrict__ counts, int N,
                                             int* __restrict__ offs, int* __restrict__ blkSum,
                                             float* __restrict__ dinv) {
  __shared__ int sd[256];
  int t = threadIdx.x;
  int i0 = blockIdx.x * 1024 + t * 4;
  int v0 = (i0 + 0 < N) ? counts[i0 + 0] : 0;
  int v1 = (i0 + 1 < N) ? counts[i0 + 1] : 0;
  int v2 = (i0 + 2 < N) ? counts[i0 + 2] : 0;
  int v3 = (i0 + 3 < N) ? counts[i0 + 3] : 0;
  if (i0 + 0 < N) dinv[i0 + 0] = rsqrtf((float)(v0 + 1));
  if (i0 + 1 < N) dinv[i0 + 1] = rsqrtf((float)(v1 + 1));
  if (i0 + 2 < N) dinv[i0 + 2] = rsqrtf((float)(v2 + 1));
  if (i0 + 3 < N) dinv[i0 + 3] = rsqrtf((float)(v3 + 1));
  int tot = v0 + v1 + v2 + v3;
  sd[t] = tot;
  __syncthreads();
  for (int off = 1; off < 256; off <<= 1) {
    int x = (t >= off) ? sd[t - off] : 0;
    __syncthreads();
    sd[t] += x;
    __syncthreads();
  }
  int excl = sd[t] - tot;
  if (i0 + 0 < N) offs[i0 + 0] = excl;
  if (i0 + 1 < N) offs[i0 + 1] = excl + v0;
  if (i0 + 2 < N) offs[i0 + 2] = excl + v0 + v1;
  if (i0 + 3 < N) offs[i0 + 3] = excl + v0 + v1 + v2;
  if (t == 255) blkSum[blockIdx.x] = sd[255];
}

__global__ void scan2(const int* __restrict__ blkSum, int nb, int* __restrict__ blkOff,
                      int* __restrict__ offs, int N) {
  if (threadIdx.x == 0 && blockIdx.x == 0) {
    int run = 0;
    for (int b = 0; b < nb; ++b) { blkOff[b] = run; run += blkSum[b]; }
    offs[N] = run;
  }
}

__global__ __launch_bounds__(1024) void scan3(int* __restrict__ offs, int N,
                                              const int* __restrict__ blkOff) {
  int i = blockIdx.x * 1024 + threadIdx.x;
  if (i < N) offs[i] += blkOff[blockIdx.x];
}

// packed CSR entry: (src, coef-as-int) -> one 8B store / 8B load
__global__ __launch_bounds__(256) void fill_kernel(const int* __restrict__ src,
                                                   const int* __restrict__ dst, int E,
                                                   const int* __restrict__ offs,
                                                   int* __restrict__ cursor,
                                                   const float* __restrict__ dinv,
                                                   int2* __restrict__ csr) {
  int e = blockIdx.x * 256 + threadIdx.x;
  if (e >= E) return;
  int s = src[e], d = dst[e];
  int pos = offs[d] + atomicAdd(&cursor[d], 1);
  csr[pos] = make_int2(s, __float_as_int(dinv[s] * dinv[d]));
}

// ---------------- graph-id boundaries (batch sorted) ----------------

__global__ __launch_bounds__(256) void boundary_kernel(const int* __restrict__ batch, int N,
                                                       unsigned int* __restrict__ gstart) {
  int i = blockIdx.x * 256 + threadIdx.x;
  if (i >= N) return;
  if (i == 0 || batch[i] != batch[i - 1]) atomicMin(&gstart[batch[i]], (unsigned int)i);
}

__global__ void fixup_kernel(unsigned int* __restrict__ gstart, int N, int G) {
  if (threadIdx.x == 0 && blockIdx.x == 0) {
    gstart[G] = (unsigned int)N;
    for (int g = G - 1; g >= 0; --g)
      if (gstart[g] == 0xFFFFFFFFu) gstart[g] = gstart[g + 1];
  }
}

// ---------------- dtype conversion / weight transpose ----------------

__global__ __launch_bounds__(256) void cvt_x_kernel(const float* __restrict__ x,
                                                    unsigned short* __restrict__ xb, int total4) {
  int i = blockIdx.x * 256 + threadIdx.x;
  if (i >= total4) return;
  float4 v = ((const float4*)x)[i];
  unsigned int lo = (unsigned int)f2bf(v.x) | ((unsigned int)f2bf(v.y) << 16);
  unsigned int hi = (unsigned int)f2bf(v.z) | ((unsigned int)f2bf(v.w) << 16);
  ((uint2*)xb)[i] = make_uint2(lo, hi);
}

// W[K][256] (f32) -> Wt[256][K] (bf16)
__global__ __launch_bounds__(256) void cvtW_kernel(const float* __restrict__ W,
                                                   unsigned short* __restrict__ Wt, int K) {
  int idx = blockIdx.x * 256 + threadIdx.x;
  if (idx >= K * 256) return;
  int k = idx >> 8, n = idx & 255;
  Wt[n * K + k] = f2bf(W[k * 256 + n]);
}

// ---------------- aggregation (gather, CSR by dst), one wave per node ----------------
// 4-edge unroll, 2 accumulator chains, 4 loads in flight.

__device__ __forceinline__ void acc256(uint2 v, float co, float4 sc, float4 sh, bool apply,
                                       float& ax, float& ay, float& az, float& aw) {
  float fx = bf2f((unsigned short)(v.x & 0xffff));
  float fy = bf2f((unsigned short)(v.x >> 16));
  float fz = bf2f((unsigned short)(v.y & 0xffff));
  float fw = bf2f((unsigned short)(v.y >> 16));
  if (apply) {
    fx = fmaxf(fx * sc.x + sh.x, 0.f); fy = fmaxf(fy * sc.y + sh.y, 0.f);
    fz = fmaxf(fz * sc.z + sh.z, 0.f); fw = fmaxf(fw * sc.w + sh.w, 0.f);
  }
  ax += co * fx; ay += co * fy; az += co * fz; aw += co * fw;
}

template <bool APPLY>
__global__ __launch_bounds__(256) void agg256_bf(const unsigned short* __restrict__ h,
                                                 const int* __restrict__ offs,
                                                 const int2* __restrict__ csr,
                                                 const float* __restrict__ dinv,
                                                 const float* __restrict__ scale,
                                                 const float* __restrict__ shift,
                                                 unsigned short* __restrict__ out, int N) {
  int n = (blockIdx.x * 256 + threadIdx.x) >> 6;
  int lane = threadIdx.x & 63;
  if (n >= N) return;
  int c0 = lane * 4;
  float4 sc = make_float4(1.f, 1.f, 1.f, 1.f), sh = make_float4(0.f, 0.f, 0.f, 0.f);
  if (APPLY) { sc = *(const float4*)&scale[c0]; sh = *(const float4*)&shift[c0]; }
  float di = dinv[n];
  float self = di * di;
  float ax0 = 0.f, ay0 = 0.f, az0 = 0.f, aw0 = 0.f;
  float ax1 = 0.f, ay1 = 0.f, az1 = 0.f, aw1 = 0.f;
  {
    uint2 v = *((const uint2*)(h + (size_t)n * 256) + lane);
    acc256(v, self, sc, sh, APPLY, ax0, ay0, az0, aw0);
  }
  int e0 = offs[n], e1 = offs[n + 1];
  for (int eb = e0; eb < e1; eb += 64) {
    int k = min(64, e1 - eb);
    int2 me = make_int2(0, 0);
    if (lane < k) me = csr[eb + lane];
    int i = 0;
    for (; i + 4 <= k; i += 4) {
      int s0 = __shfl(me.x, i),     s1 = __shfl(me.x, i + 1);
      int s2 = __shfl(me.x, i + 2), s3 = __shfl(me.x, i + 3);
      float co0 = __int_as_float(__shfl(me.y, i));
      float co1 = __int_as_float(__shfl(me.y, i + 1));
      float co2 = __int_as_float(__shfl(me.y, i + 2));
      float co3 = __int_as_float(__shfl(me.y, i + 3));
      uint2 v0 = *((const uint2*)(h + (size_t)s0 * 256) + lane);
      uint2 v1 = *((const uint2*)(h + (size_t)s1 * 256) + lane);
      uint2 v2 = *((const uint2*)(h + (size_t)s2 * 256) + lane);
      uint2 v3 = *((const uint2*)(h + (size_t)s3 * 256) + lane);
      acc256(v0, co0, sc, sh, APPLY, ax0, ay0, az0, aw0);
      acc256(v1, co1, sc, sh, APPLY, ax1, ay1, az1, aw1);
      acc256(v2, co2, sc, sh, APPLY, ax0, ay0, az0, aw0);
      acc256(v3, co3, sc, sh, APPLY, ax1, ay1, az1, aw1);
    }
    for (; i < k; ++i) {
      int s = __shfl(me.x, i);
      float co = __int_as_float(__shfl(me.y, i));
      uint2 v = *((const uint2*)(h + (size_t)s * 256) + lane);
      acc256(v, co, sc, sh, APPLY, ax0, ay0, az0, aw0);
    }
  }
  float ax = ax0 + ax1, ay = ay0 + ay1, az = az0 + az1, aw = aw0 + aw1;
  unsigned int lo = (unsigned int)f2bf(ax) | ((unsigned int)f2bf(ay) << 16);
  unsigned int hi = (unsigned int)f2bf(az) | ((unsigned int)f2bf(aw) << 16);
  *((uint2*)(out + (size_t)n * 256) + lane) = make_uint2(lo, hi);
}

__device__ __forceinline__ void acc128(unsigned int v, float co, float& ax, float& ay) {
  ax += co * bf2f((unsigned short)(v & 0xffff));
  ay += co * bf2f((unsigned short)(v >> 16));
}

__global__ __launch_bounds__(256) void agg128_bf(const unsigned short* __restrict__ h,
                                                 const int* __restrict__ offs,
                                                 const int2* __restrict__ csr,
                                                 const float* __restrict__ dinv,
                                                 unsigned short* __restrict__ out, int N) {
  int n = (blockIdx.x * 256 + threadIdx.x) >> 6;
  int lane = threadIdx.x & 63;
  if (n >= N) return;
  float di = dinv[n];
  float self = di * di;
  float ax0 = 0.f, ay0 = 0.f, ax1 = 0.f, ay1 = 0.f;
  {
    unsigned int v = *((const unsigned int*)(h + (size_t)n * 128) + lane);
    acc128(v, self, ax0, ay0);
  }
  int e0 = offs[n], e1 = offs[n + 1];
  for (int eb = e0; eb < e1; eb += 64) {
    int k = min(64, e1 - eb);
    int2 me = make_int2(0, 0);
    if (lane < k) me = csr[eb + lane];
    int i = 0;
    for (; i + 4 <= k; i += 4) {
      int s0 = __shfl(me.x, i),     s1 = __shfl(me.x, i + 1);
      int s2 = __shfl(me.x, i + 2), s3 = __shfl(me.x, i + 3);
      float co0 = __int_as_float(__shfl(me.y, i));
      float co1 = __int_as_float(__shfl(me.y, i + 1));
      float co2 = __int_as_float(__shfl(me.y, i + 2));
      float co3 = __int_as_float(__shfl(me.y, i + 3));
      unsigned int v0 = *((const unsigned int*)(h + (size_t)s0 * 128) + lane);
      unsigned int v1 = *((const unsigned int*)(h + (size_t)s1 * 128) + lane);
      unsigned int v2 = *((const unsigned int*)(h + (size_t)s2 * 128) + lane);
      unsigned int v3 = *((const unsigned int*)(h + (size_t)s3 * 128) + lane);
      acc128(v0, co0, ax0, ay0); acc128(v1, co1, ax1, ay1);
      acc128(v2, co2, ax0, ay0); acc128(v3, co3, ax1, ay1);
    }
    for (; i < k; ++i) {
      int s = __shfl(me.x, i);
      float co = __int_as_float(__shfl(me.y, i));
      unsigned int v = *((const unsigned int*)(h + (size_t)s * 128) + lane);
      acc128(v, co, ax0, ay0);
    }
  }
  float ax = ax0 + ax1, ay = ay0 + ay1;
  *((unsigned int*)(out + (size_t)n * 128) + lane) =
      (unsigned int)f2bf(ax) | ((unsigned int)f2bf(ay) << 16);
}

// ---------------- bf16 MFMA GEMM + fused BN partial stats ----------------
// C[M,256] = A[M,K] @ W[K,256]; tile 128x128, BK=64, 256 thr = 4 waves.
// Epilogue accumulates per-column sum/sumsq of the f32 accumulators into
// global sums/sumsq via shfl-reduce + atomics (replaces bn_stats pass).

__global__ __launch_bounds__(256) void gemm_bf(const unsigned short* __restrict__ A,
                                               const unsigned short* __restrict__ Wt,
                                               unsigned short* __restrict__ C,
                                               int M, int K,
                                               float* __restrict__ sums,
                                               float* __restrict__ sumsq) {
  __shared__ unsigned short As[128][72];
  __shared__ unsigned short Bs[128][72];
  int t = threadIdx.x;
  int w = t >> 6, lane = t & 63;
  int l16 = lane & 15, lhi = lane >> 4;
  int rowBase = blockIdx.x * 128, colBase = blockIdx.y * 128;
  f32x4 acc[2][8] = {};
  int srow = t >> 1;            // 0..127
  int soff = (t & 1) * 32;      // 0 or 32 within BK=64
  const unsigned short* Abase = A + (size_t)(rowBase + srow) * K + soff;
  const unsigned short* Bbase = Wt + (size_t)(colBase + srow) * K + soff;
  bool arow_ok = (rowBase + srow) < M;
  for (int k0 = 0; k0 < K; k0 += 64) {
    int4 z = make_int4(0, 0, 0, 0);
    int4 a0 = z, a1 = z, a2 = z, a3 = z;
    if (arow_ok) {
      a0 = *(const int4*)(Abase + k0);
      a1 = *(const int4*)(Abase + k0 + 8);
      a2 = *(const int4*)(Abase + k0 + 16);
      a3 = *(const int4*)(Abase + k0 + 24);
    }
    *(int4*)&As[srow][soff]      = a0;
    *(int4*)&As[srow][soff + 8]  = a1;
    *(int4*)&As[srow][soff + 16] = a2;
    *(int4*)&As[srow][soff + 24] = a3;
    *(int4*)&Bs[srow][soff]      = *(const int4*)(Bbase + k0);
    *(int4*)&Bs[srow][soff + 8]  = *(const int4*)(Bbase + k0 + 8);
    *(int4*)&Bs[srow][soff + 16] = *(const int4*)(Bbase + k0 + 16);
    *(int4*)&Bs[srow][soff + 24] = *(const int4*)(Bbase + k0 + 24);
    __syncthreads();
#pragma unroll
    for (int kk = 0; kk < 64; kk += 32) {
      bf16x8 af0 = *(const bf16x8*)&As[w * 32 + l16][kk + lhi * 8];
      bf16x8 af1 = *(const bf16x8*)&As[w * 32 + 16 + l16][kk + lhi * 8];
#pragma unroll
      for (int g = 0; g < 8; ++g) {
        bf16x8 bf = *(const bf16x8*)&Bs[g * 16 + l16][kk + lhi * 8];
        acc[0][g] = __builtin_amdgcn_mfma_f32_16x16x32_bf16(af0, bf, acc[0][g], 0, 0, 0);
        acc[1][g] = __builtin_amdgcn_mfma_f32_16x16x32_bf16(af1, bf, acc[1][g], 0, 0, 0);
      }
    }
    __syncthreads();
  }
  // C write (bf16)
#pragma unroll
  for (int f = 0; f < 2; ++f) {
#pragma unroll
    for (int r = 0; r < 4; ++r) {
      int row = rowBase + w * 32 + f * 16 + lhi * 4 + r;
      if (row < M) {
        size_t o = (size_t)row * 256 + colBase + l16;
#pragma unroll
        for (int g = 0; g < 8; ++g) C[o + g * 16] = f2bf(acc[f][g][r]);
      }
    }
  }
  // fused BN partial stats (rows >= M contribute exact zeros)
#pragma unroll
  for (int g = 0; g < 8; ++g) {
    float s = 0.f, s2 = 0.f;
#pragma unroll
    for (int f = 0; f < 2; ++f)
#pragma unroll
      for (int r = 0; r < 4; ++r) { float v = acc[f][g][r]; s += v; s2 += v * v; }
    s  += __shfl_xor(s, 16);  s  += __shfl_xor(s, 32);
    s2 += __shfl_xor(s2, 16); s2 += __shfl_xor(s2, 32);
    if (lhi == 0) {
      atomicAdd(&sums[colBase + l16 + g * 16], s);
      atomicAdd(&sumsq[colBase + l16 + g * 16], s2);
    }
  }
}

// ---------------- batchnorm finalize (also re-zeroes stats for next layer) ----------------

__global__ void bn_finalize(float* __restrict__ sums, float* __restrict__ sumsq,
                            const float* __restrict__ gamma, const float* __restrict__ beta,
                            int N, float* __restrict__ scale, float* __restrict__ shift) {
  int c = threadIdx.x;  // 256
  float inv_n = 1.0f / (float)N;
  float mean = sums[c] * inv_n;
  float var = sumsq[c] * inv_n - mean * mean;
  float sc = gamma[c] * rsqrtf(var + BN_EPS);
  scale[c] = sc;
  shift[c] = beta[c] - mean * sc;
  sums[c] = 0.f;
  sumsq[c] = 0.f;
}

// ---------------- pooling (BN+ReLU fused, partials, no atomics) + classifier ----------------

#define PSLICES 8

__global__ __launch_bounds__(256) void pool_part_bf(const unsigned short* __restrict__ h,
                                                    const unsigned int* __restrict__ gstart,
                                                    const float* __restrict__ scale,
                                                    const float* __restrict__ shift,
                                                    float* __restrict__ pool_part) {
  int g = blockIdx.x >> 3, s = blockIdx.x & (PSLICES - 1);
  int c = threadIdx.x;
  int gs = (int)gstart[g], ge = (int)gstart[g + 1];
  int len = ge - gs;
  int r0 = gs + (int)(((long long)len * s) / PSLICES);
  int r1 = gs + (int)(((long long)len * (s + 1)) / PSLICES);
  float sc = scale[c], sh = shift[c];
  float acc = 0.f;
  for (int r = r0; r < r1; ++r)
    acc += fmaxf(bf2f(h[(size_t)r * 256 + c]) * sc + sh, 0.f);
  pool_part[(size_t)blockIdx.x * 256 + c] = acc;
}

__global__ __launch_bounds__(64) void final_kernel(const float* __restrict__ pool_part,
                                                   const unsigned int* __restrict__ gstart,
                                                   const float* __restrict__ Wl,
                                                   const float* __restrict__ bl,
                                                   float* __restrict__ out, int NC) {
  __shared__ float p[256];
  int g = blockIdx.x, t = threadIdx.x;
  float len = (float)((int)gstart[g + 1] - (int)gstart[g]);
  float inv = 1.0f / fmaxf(len, 1.0f);
  for (int i = t; i < 256; i += 64) {
    float s = 0.f;
#pragma unroll
    for (int k = 0; k < PSLICES; ++k) s += pool_part[(size_t)(g * PSLICES + k) * 256 + i];
    p[i] = s * inv;
  }
  __syncthreads();
  if (t < NC) {
    float s = bl[t];
    for (int k = 0; k < 256; ++k) s += p[k] * Wl[k * NC + t];
    out[g * NC + t] = s;
  }
}

// ---------------- launcher ----------------

extern "C" void kernel_launch(void* const* d_in, const int* in_sizes, int n_in,
                              void* d_out, int out_size, void* d_ws, size_t ws_size,
                              hipStream_t stream) {
  const float* x      = (const float*)d_in[0];
  const int*   ei     = (const int*)d_in[1];
  const int*   batch  = (const int*)d_in[2];
  const float* W0     = (const float*)d_in[3];
  const float* gamma0 = (const float*)d_in[5];
  const float* beta0  = (const float*)d_in[6];
  const float* W1     = (const float*)d_in[7];
  const float* gamma1 = (const float*)d_in[9];
  const float* beta1  = (const float*)d_in[10];
  const float* W2     = (const float*)d_in[11];
  const float* gamma2 = (const float*)d_in[13];
  const float* beta2  = (const float*)d_in[14];
  const float* Wl     = (const float*)d_in[15];
  const float* bl     = (const float*)d_in[16];
  float* out = (float*)d_out;

  int N = in_sizes[0] / 128;  // 50000
  int E = in_sizes[1] / 2;    // 800000
  int G = 128;
  int NC = 40;
  const int* src = ei;
  const int* dst = ei + E;

  char* p = (char*)d_ws;
  auto alloc = [&](size_t bytes) -> void* {
    void* r = (void*)p;
    p += (bytes + 255) & ~(size_t)255;
    return r;
  };
  unsigned short* xb  = (unsigned short*)alloc((size_t)N * 128 * 2);
  unsigned short* hA  = (unsigned short*)alloc((size_t)N * 256 * 2);
  unsigned short* hB  = (unsigned short*)alloc((size_t)N * 256 * 2);
  unsigned short* Wt0 = (unsigned short*)alloc((size_t)256 * 128 * 2);
  unsigned short* Wt1 = (unsigned short*)alloc((size_t)256 * 256 * 2);
  unsigned short* Wt2 = (unsigned short*)alloc((size_t)256 * 256 * 2);
  int2*  csr      = (int2*) alloc((size_t)E * 8);
  int*   cc       = (int*)  alloc((size_t)2 * N * 4);  // counts | cursor (one memset)
  int*   counts   = cc;
  int*   cursor   = cc + N;
  int*   offs     = (int*)  alloc((size_t)(N + 1) * 4);
  float* dinv     = (float*)alloc((size_t)N * 4);
  int*   blkSum   = (int*)  alloc(64 * 4);
  int*   blkOff   = (int*)  alloc(64 * 4);
  float* sums     = (float*)alloc(512 * 4);
  float* sumsq    = sums + 256;
  float* scale0   = (float*)alloc(256 * 4);
  float* shift0   = (float*)alloc(256 * 4);
  float* scale1   = (float*)alloc(256 * 4);
  float* shift1   = (float*)alloc(256 * 4);
  float* scale2   = (float*)alloc(256 * 4);
  float* shift2   = (float*)alloc(256 * 4);
  unsigned int* gstart = (unsigned int*)alloc((size_t)(G + 1) * 4);
  float* pool_part = (float*)alloc((size_t)G * PSLICES * 256 * 4);

  // ---- graph structure (once per launch) ----
  hipMemsetAsync(cc, 0, (size_t)2 * N * 4, stream);
  hipMemsetAsync(gstart, 0xFF, (size_t)(G + 1) * 4, stream);
  hipMemsetAsync(sums, 0, 512 * 4, stream);
  count_kernel<<<(E + 255) / 256, 256, 0, stream>>>(dst, E, counts);
  int nb = (N + 1023) / 1024;
  scan1<<<nb, 256, 0, stream>>>(counts, N, offs, blkSum, dinv);
  scan2<<<1, 1, 0, stream>>>(blkSum, nb, blkOff, offs, N);
  scan3<<<nb, 1024, 0, stream>>>(offs, N, blkOff);
  fill_kernel<<<(E + 255) / 256, 256, 0, stream>>>(src, dst, E, offs, cursor, dinv, csr);
  boundary_kernel<<<(N + 255) / 256, 256, 0, stream>>>(batch, N, gstart);
  fixup_kernel<<<1, 1, 0, stream>>>(gstart, N, G);

  // ---- dtype prep ----
  cvt_x_kernel<<<(N * 128 / 4 + 255) / 256, 256, 0, stream>>>(x, xb, N * 128 / 4);
  cvtW_kernel<<<(128 * 256 + 255) / 256, 256, 0, stream>>>(W0, Wt0, 128);
  cvtW_kernel<<<(256 * 256 + 255) / 256, 256, 0, stream>>>(W1, Wt1, 256);
  cvtW_kernel<<<(256 * 256 + 255) / 256, 256, 0, stream>>>(W2, Wt2, 256);

  int aggBlocks = (N + 3) / 4;
  dim3 gemmGrid((N + 127) / 128, 2);

  // ---- layer 0 ----
  agg128_bf<<<aggBlocks, 256, 0, stream>>>(xb, offs, csr, dinv, hA, N);
  gemm_bf<<<gemmGrid, 256, 0, stream>>>(hA, Wt0, hB, N, 128, sums, sumsq);
  bn_finalize<<<1, 256, 0, stream>>>(sums, sumsq, gamma0, beta0, N, scale0, shift0);

  // ---- layer 1 (BN0+ReLU fused into gather) ----
  agg256_bf<true><<<aggBlocks, 256, 0, stream>>>(hB, offs, csr, dinv, scale0, shift0, hA, N);
  gemm_bf<<<gemmGrid, 256, 0, stream>>>(hA, Wt1, hB, N, 256, sums, sumsq);
  bn_finalize<<<1, 256, 0, stream>>>(sums, sumsq, gamma1, beta1, N, scale1, shift1);

  // ---- layer 2 ----
  agg256_bf<true><<<aggBlocks, 256, 0, stream>>>(hB, offs, csr, dinv, scale1, shift1, hA, N);
  gemm_bf<<<gemmGrid, 256, 0, stream>>>(hA, Wt2, hB, N, 256, sums, sumsq);
  bn_finalize<<<1, 256, 0, stream>>>(sums, sumsq, gamma2, beta2, N, scale2, shift2);

  // ---- pool + classifier ----
  pool_part_bf<<<G * PSLICES, 256, 0, stream>>>(hB, gstart, scale2, shift2, pool_part);
  final_kernel<<<G, 64, 0, stream>>>(pool_part, gstart, Wl, bl, out, NC);
}

// Round 5
// 522.948 us; speedup vs baseline: 2.2966x; 1.1509x over previous
//
#include <hip/hip_runtime.h>

#define BN_EPS 1e-5f

typedef __attribute__((ext_vector_type(8))) short bf16x8;
typedef __attribute__((ext_vector_type(4))) float f32x4;

__device__ __forceinline__ float bf2f(unsigned short u) {
  return __uint_as_float(((unsigned int)u) << 16);
}
__device__ __forceinline__ unsigned short f2bf(float f) {
  unsigned int u = __float_as_uint(f);
  u = u + 0x7FFFu + ((u >> 16) & 1u);   // round-to-nearest-even
  return (unsigned short)(u >> 16);
}

// async global->LDS, 16B per lane; LDS dest = (wave-uniform base) + lane*16
__device__ __forceinline__ void gload16(const unsigned short* g, unsigned short* l) {
  __builtin_amdgcn_global_load_lds(
      (const __attribute__((address_space(1))) unsigned int*)g,
      (__attribute__((address_space(3))) unsigned int*)l, 16, 0, 0);
}

// ---------------- graph structure kernels ----------------

__global__ __launch_bounds__(256) void count_kernel(const int* __restrict__ dst, int E,
                                                    int* __restrict__ counts) {
  int e = blockIdx.x * 256 + threadIdx.x;
  if (e < E) atomicAdd(&counts[dst[e]], 1);
}

// scan1 also produces dinv = rsqrt(deg+1) in the same pass over counts
__global__ __launch_bounds__(256) void scan1(const int* __restrict__ counts, int N,
                                             int* __restrict__ offs, int* __restrict__ blkSum,
                                             float* __restrict__ dinv) {
  __shared__ int sd[256];
  int t = threadIdx.x;
  int i0 = blockIdx.x * 1024 + t * 4;
  int v0 = (i0 + 0 < N) ? counts[i0 + 0] : 0;
  int v1 = (i0 + 1 < N) ? counts[i0 + 1] : 0;
  int v2 = (i0 + 2 < N) ? counts[i0 + 2] : 0;
  int v3 = (i0 + 3 < N) ? counts[i0 + 3] : 0;
  if (i0 + 0 < N) dinv[i0 + 0] = rsqrtf((float)(v0 + 1));
  if (i0 + 1 < N) dinv[i0 + 1] = rsqrtf((float)(v1 + 1));
  if (i0 + 2 < N) dinv[i0 + 2] = rsqrtf((float)(v2 + 1));
  if (i0 + 3 < N) dinv[i0 + 3] = rsqrtf((float)(v3 + 1));
  int tot = v0 + v1 + v2 + v3;
  sd[t] = tot;
  __syncthreads();
  for (int off = 1; off < 256; off <<= 1) {
    int x = (t >= off) ? sd[t - off] : 0;
    __syncthreads();
    sd[t] += x;
    __syncthreads();
  }
  int excl = sd[t] - tot;
  if (i0 + 0 < N) offs[i0 + 0] = excl;
  if (i0 + 1 < N) offs[i0 + 1] = excl + v0;
  if (i0 + 2 < N) offs[i0 + 2] = excl + v0 + v1;
  if (i0 + 3 < N) offs[i0 + 3] = excl + v0 + v1 + v2;
  if (t == 255) blkSum[blockIdx.x] = sd[255];
}

__global__ void scan2(const int* __restrict__ blkSum, int nb, int* __restrict__ blkOff,
                      int* __restrict__ offs, int N) {
  if (threadIdx.x == 0 && blockIdx.x == 0) {
    int run = 0;
    for (int b = 0; b < nb; ++b) { blkOff[b] = run; run += blkSum[b]; }
    offs[N] = run;
  }
}

__global__ __launch_bounds__(1024) void scan3(int* __restrict__ offs, int N,
                                              const int* __restrict__ blkOff) {
  int i = blockIdx.x * 1024 + threadIdx.x;
  if (i < N) offs[i] += blkOff[blockIdx.x];
}

// packed CSR entry: (src, coef-as-int)
__global__ __launch_bounds__(256) void fill_kernel(const int* __restrict__ src,
                                                   const int* __restrict__ dst, int E,
                                                   const int* __restrict__ offs,
                                                   int* __restrict__ cursor,
                                                   const float* __restrict__ dinv,
                                                   int2* __restrict__ csr) {
  int e = blockIdx.x * 256 + threadIdx.x;
  if (e >= E) return;
  int s = src[e], d = dst[e];
  int pos = offs[d] + atomicAdd(&cursor[d], 1);
  csr[pos] = make_int2(s, __float_as_int(dinv[s] * dinv[d]));
}

// ---------------- graph-id boundaries (batch sorted) ----------------

__global__ __launch_bounds__(256) void boundary_kernel(const int* __restrict__ batch, int N,
                                                       unsigned int* __restrict__ gstart) {
  int i = blockIdx.x * 256 + threadIdx.x;
  if (i >= N) return;
  if (i == 0 || batch[i] != batch[i - 1]) atomicMin(&gstart[batch[i]], (unsigned int)i);
}

__global__ void fixup_kernel(unsigned int* __restrict__ gstart, int N, int G) {
  if (threadIdx.x == 0 && blockIdx.x == 0) {
    gstart[G] = (unsigned int)N;
    for (int g = G - 1; g >= 0; --g)
      if (gstart[g] == 0xFFFFFFFFu) gstart[g] = gstart[g + 1];
  }
}

// ---------------- dtype conversion / weight transpose ----------------

__global__ __launch_bounds__(256) void cvt_x_kernel(const float* __restrict__ x,
                                                    unsigned short* __restrict__ xb, int total4) {
  int i = blockIdx.x * 256 + threadIdx.x;
  if (i >= total4) return;
  float4 v = ((const float4*)x)[i];
  unsigned int lo = (unsigned int)f2bf(v.x) | ((unsigned int)f2bf(v.y) << 16);
  unsigned int hi = (unsigned int)f2bf(v.z) | ((unsigned int)f2bf(v.w) << 16);
  ((uint2*)xb)[i] = make_uint2(lo, hi);
}

// W[K][256] (f32) -> Wt[256][K] (bf16)
__global__ __launch_bounds__(256) void cvtW_kernel(const float* __restrict__ W,
                                                   unsigned short* __restrict__ Wt, int K) {
  int idx = blockIdx.x * 256 + threadIdx.x;
  if (idx >= K * 256) return;
  int k = idx >> 8, n = idx & 255;
  Wt[n * K + k] = f2bf(W[k * 256 + n]);
}

// ---------------- aggregation (gather, CSR by dst), one wave per node ----------------

__device__ __forceinline__ void acc256(uint2 v, float co, float4 sc, float4 sh, bool apply,
                                       float& ax, float& ay, float& az, float& aw) {
  float fx = bf2f((unsigned short)(v.x & 0xffff));
  float fy = bf2f((unsigned short)(v.x >> 16));
  float fz = bf2f((unsigned short)(v.y & 0xffff));
  float fw = bf2f((unsigned short)(v.y >> 16));
  if (apply) {
    fx = fmaxf(fx * sc.x + sh.x, 0.f); fy = fmaxf(fy * sc.y + sh.y, 0.f);
    fz = fmaxf(fz * sc.z + sh.z, 0.f); fw = fmaxf(fw * sc.w + sh.w, 0.f);
  }
  ax += co * fx; ay += co * fy; az += co * fz; aw += co * fw;
}

template <bool APPLY>
__global__ __launch_bounds__(256) void agg256_bf(const unsigned short* __restrict__ h,
                                                 const int* __restrict__ offs,
                                                 const int2* __restrict__ csr,
                                                 const float* __restrict__ dinv,
                                                 const float* __restrict__ scale,
                                                 const float* __restrict__ shift,
                                                 unsigned short* __restrict__ out, int N) {
  int n = (blockIdx.x * 256 + threadIdx.x) >> 6;
  int lane = threadIdx.x & 63;
  if (n >= N) return;
  int c0 = lane * 4;
  float4 sc = make_float4(1.f, 1.f, 1.f, 1.f), sh = make_float4(0.f, 0.f, 0.f, 0.f);
  if (APPLY) { sc = *(const float4*)&scale[c0]; sh = *(const float4*)&shift[c0]; }
  float di = dinv[n];
  float self = di * di;
  float ax0 = 0.f, ay0 = 0.f, az0 = 0.f, aw0 = 0.f;
  float ax1 = 0.f, ay1 = 0.f, az1 = 0.f, aw1 = 0.f;
  {
    uint2 v = *((const uint2*)(h + (size_t)n * 256) + lane);
    acc256(v, self, sc, sh, APPLY, ax0, ay0, az0, aw0);
  }
  int e0 = offs[n], e1 = offs[n + 1];
  for (int eb = e0; eb < e1; eb += 64) {
    int k = min(64, e1 - eb);
    int2 me = make_int2(0, 0);
    if (lane < k) me = csr[eb + lane];
    int i = 0;
    for (; i + 4 <= k; i += 4) {
      int s0 = __shfl(me.x, i),     s1 = __shfl(me.x, i + 1);
      int s2 = __shfl(me.x, i + 2), s3 = __shfl(me.x, i + 3);
      float co0 = __int_as_float(__shfl(me.y, i));
      float co1 = __int_as_float(__shfl(me.y, i + 1));
      float co2 = __int_as_float(__shfl(me.y, i + 2));
      float co3 = __int_as_float(__shfl(me.y, i + 3));
      uint2 v0 = *((const uint2*)(h + (size_t)s0 * 256) + lane);
      uint2 v1 = *((const uint2*)(h + (size_t)s1 * 256) + lane);
      uint2 v2 = *((const uint2*)(h + (size_t)s2 * 256) + lane);
      uint2 v3 = *((const uint2*)(h + (size_t)s3 * 256) + lane);
      acc256(v0, co0, sc, sh, APPLY, ax0, ay0, az0, aw0);
      acc256(v1, co1, sc, sh, APPLY, ax1, ay1, az1, aw1);
      acc256(v2, co2, sc, sh, APPLY, ax0, ay0, az0, aw0);
      acc256(v3, co3, sc, sh, APPLY, ax1, ay1, az1, aw1);
    }
    for (; i < k; ++i) {
      int s = __shfl(me.x, i);
      float co = __int_as_float(__shfl(me.y, i));
      uint2 v = *((const uint2*)(h + (size_t)s * 256) + lane);
      acc256(v, co, sc, sh, APPLY, ax0, ay0, az0, aw0);
    }
  }
  float ax = ax0 + ax1, ay = ay0 + ay1, az = az0 + az1, aw = aw0 + aw1;
  unsigned int lo = (unsigned int)f2bf(ax) | ((unsigned int)f2bf(ay) << 16);
  unsigned int hi = (unsigned int)f2bf(az) | ((unsigned int)f2bf(aw) << 16);
  *((uint2*)(out + (size_t)n * 256) + lane) = make_uint2(lo, hi);
}

__device__ __forceinline__ void acc128(unsigned int v, float co, float& ax, float& ay) {
  ax += co * bf2f((unsigned short)(v & 0xffff));
  ay += co * bf2f((unsigned short)(v >> 16));
}

__global__ __launch_bounds__(256) void agg128_bf(const unsigned short* __restrict__ h,
                                                 const int* __restrict__ offs,
                                                 const int2* __restrict__ csr,
                                                 const float* __restrict__ dinv,
                                                 unsigned short* __restrict__ out, int N) {
  int n = (blockIdx.x * 256 + threadIdx.x) >> 6;
  int lane = threadIdx.x & 63;
  if (n >= N) return;
  float di = dinv[n];
  float self = di * di;
  float ax0 = 0.f, ay0 = 0.f, ax1 = 0.f, ay1 = 0.f;
  {
    unsigned int v = *((const unsigned int*)(h + (size_t)n * 128) + lane);
    acc128(v, self, ax0, ay0);
  }
  int e0 = offs[n], e1 = offs[n + 1];
  for (int eb = e0; eb < e1; eb += 64) {
    int k = min(64, e1 - eb);
    int2 me = make_int2(0, 0);
    if (lane < k) me = csr[eb + lane];
    int i = 0;
    for (; i + 4 <= k; i += 4) {
      int s0 = __shfl(me.x, i),     s1 = __shfl(me.x, i + 1);
      int s2 = __shfl(me.x, i + 2), s3 = __shfl(me.x, i + 3);
      float co0 = __int_as_float(__shfl(me.y, i));
      float co1 = __int_as_float(__shfl(me.y, i + 1));
      float co2 = __int_as_float(__shfl(me.y, i + 2));
      float co3 = __int_as_float(__shfl(me.y, i + 3));
      unsigned int v0 = *((const unsigned int*)(h + (size_t)s0 * 128) + lane);
      unsigned int v1 = *((const unsigned int*)(h + (size_t)s1 * 128) + lane);
      unsigned int v2 = *((const unsigned int*)(h + (size_t)s2 * 128) + lane);
      unsigned int v3 = *((const unsigned int*)(h + (size_t)s3 * 128) + lane);
      acc128(v0, co0, ax0, ay0); acc128(v1, co1, ax1, ay1);
      acc128(v2, co2, ax0, ay0); acc128(v3, co3, ax1, ay1);
    }
    for (; i < k; ++i) {
      int s = __shfl(me.x, i);
      float co = __int_as_float(__shfl(me.y, i));
      unsigned int v = *((const unsigned int*)(h + (size_t)s * 128) + lane);
      acc128(v, co, ax0, ay0);
    }
  }
  float ax = ax0 + ax1, ay = ay0 + ay1;
  *((unsigned int*)(out + (size_t)n * 128) + lane) =
      (unsigned int)f2bf(ax) | ((unsigned int)f2bf(ay) << 16);
}

// ---------------- bf16 MFMA GEMM + fused BN partial stats ----------------
// C[Mpad,256] = A[Mpad,K] @ W[K,256]; tile 128x128, BK=64, 4 waves in 2x2 quadrants.
// A is zero-padded to Mpad rows, so no guards needed and pad rows add exact
// zeros to the fused BN stats. Staging via global_load_lds (linear LDS dest)
// with XOR-pre-swizzled global source; reads apply the same XOR involution:
// 16B group g of row r lives at LDS group g ^ (r&7).

__global__ __launch_bounds__(256) void gemm_bf(const unsigned short* __restrict__ A,
                                               const unsigned short* __restrict__ Wt,
                                               unsigned short* __restrict__ C,
                                               int K,
                                               float* __restrict__ sums,
                                               float* __restrict__ sumsq) {
  __shared__ unsigned short As[128 * 64];
  __shared__ unsigned short Bs[128 * 64];
  int t = threadIdx.x;
  int w = t >> 6, lane = t & 63;
  int l16 = lane & 15, lhi = lane >> 4;
  int wr = w >> 1, wc = w & 1;
  int rowBase = blockIdx.x * 128, colBase = blockIdx.y * 128;
  f32x4 acc[4][4] = {};
  int srow = lane >> 3;   // 0..7 within 8-row segment
  int sg = lane & 7;      // 16B group within 128B row
  const unsigned short* Abase = A + (size_t)rowBase * K;
  const unsigned short* Bbase = Wt + (size_t)colBase * K;
  for (int k0 = 0; k0 < K; k0 += 64) {
#pragma unroll
    for (int i = 0; i < 4; ++i) {
      int rb = i * 32 + w * 8;          // segment base row (wave-uniform)
      int row = rb + srow;
      int gg = sg ^ (row & 7);          // pre-swizzled source group
      gload16(Abase + (size_t)row * K + k0 + gg * 8, &As[rb * 64]);
      gload16(Bbase + (size_t)row * K + k0 + gg * 8, &Bs[rb * 64]);
    }
    __syncthreads();
#pragma unroll
    for (int kk = 0; kk < 64; kk += 32) {
      int gb = (kk >> 3) + lhi;
      bf16x8 a[4], b[4];
#pragma unroll
      for (int i = 0; i < 4; ++i) {
        int ra = wr * 64 + i * 16 + l16;
        a[i] = *(const bf16x8*)&As[ra * 64 + ((gb ^ (ra & 7)) << 3)];
        int rb2 = wc * 64 + i * 16 + l16;
        b[i] = *(const bf16x8*)&Bs[rb2 * 64 + ((gb ^ (rb2 & 7)) << 3)];
      }
#pragma unroll
      for (int i = 0; i < 4; ++i)
#pragma unroll
        for (int j = 0; j < 4; ++j)
          acc[i][j] = __builtin_amdgcn_mfma_f32_16x16x32_bf16(a[i], b[j], acc[i][j], 0, 0, 0);
    }
    __syncthreads();
  }
  // C write (bf16); pad rows get zeros (A pad is zero) — harmless.
#pragma unroll
  for (int i = 0; i < 4; ++i) {
#pragma unroll
    for (int rr = 0; rr < 4; ++rr) {
      int row = rowBase + wr * 64 + i * 16 + lhi * 4 + rr;
      size_t o = (size_t)row * 256 + colBase + wc * 64 + l16;
#pragma unroll
      for (int j = 0; j < 4; ++j) C[o + j * 16] = f2bf(acc[i][j][rr]);
    }
  }
  // fused BN partial stats (pad rows contribute exact zeros)
#pragma unroll
  for (int j = 0; j < 4; ++j) {
    float s = 0.f, s2 = 0.f;
#pragma unroll
    for (int i = 0; i < 4; ++i)
#pragma unroll
      for (int rr = 0; rr < 4; ++rr) { float v = acc[i][j][rr]; s += v; s2 += v * v; }
    s  += __shfl_xor(s, 16);  s  += __shfl_xor(s, 32);
    s2 += __shfl_xor(s2, 16); s2 += __shfl_xor(s2, 32);
    if (lhi == 0) {
      int col = colBase + wc * 64 + j * 16 + l16;
      atomicAdd(&sums[col], s);
      atomicAdd(&sumsq[col], s2);
    }
  }
}

// ---------------- batchnorm finalize (also re-zeroes stats for next layer) ----------------

__global__ void bn_finalize(float* __restrict__ sums, float* __restrict__ sumsq,
                            const float* __restrict__ gamma, const float* __restrict__ beta,
                            int N, float* __restrict__ scale, float* __restrict__ shift) {
  int c = threadIdx.x;  // 256
  float inv_n = 1.0f / (float)N;
  float mean = sums[c] * inv_n;
  float var = sumsq[c] * inv_n - mean * mean;
  float sc = gamma[c] * rsqrtf(var + BN_EPS);
  scale[c] = sc;
  shift[c] = beta[c] - mean * sc;
  sums[c] = 0.f;
  sumsq[c] = 0.f;
}

// ---------------- pooling (BN+ReLU fused, partials, no atomics) + classifier ----------------

#define PSLICES 8

__global__ __launch_bounds__(256) void pool_part_bf(const unsigned short* __restrict__ h,
                                                    const unsigned int* __restrict__ gstart,
                                                    const float* __restrict__ scale,
                                                    const float* __restrict__ shift,
                                                    float* __restrict__ pool_part) {
  int g = blockIdx.x >> 3, s = blockIdx.x & (PSLICES - 1);
  int c = threadIdx.x;
  int gs = (int)gstart[g], ge = (int)gstart[g + 1];
  int len = ge - gs;
  int r0 = gs + (int)(((long long)len * s) / PSLICES);
  int r1 = gs + (int)(((long long)len * (s + 1)) / PSLICES);
  float sc = scale[c], sh = shift[c];
  float acc = 0.f;
  for (int r = r0; r < r1; ++r)
    acc += fmaxf(bf2f(h[(size_t)r * 256 + c]) * sc + sh, 0.f);
  pool_part[(size_t)blockIdx.x * 256 + c] = acc;
}

__global__ __launch_bounds__(64) void final_kernel(const float* __restrict__ pool_part,
                                                   const unsigned int* __restrict__ gstart,
                                                   const float* __restrict__ Wl,
                                                   const float* __restrict__ bl,
                                                   float* __restrict__ out, int NC) {
  __shared__ float p[256];
  int g = blockIdx.x, t = threadIdx.x;
  float len = (float)((int)gstart[g + 1] - (int)gstart[g]);
  float inv = 1.0f / fmaxf(len, 1.0f);
  for (int i = t; i < 256; i += 64) {
    float s = 0.f;
#pragma unroll
    for (int k = 0; k < PSLICES; ++k) s += pool_part[(size_t)(g * PSLICES + k) * 256 + i];
    p[i] = s * inv;
  }
  __syncthreads();
  if (t < NC) {
    float s = bl[t];
    for (int k = 0; k < 256; ++k) s += p[k] * Wl[k * NC + t];
    out[g * NC + t] = s;
  }
}

// ---------------- launcher ----------------

extern "C" void kernel_launch(void* const* d_in, const int* in_sizes, int n_in,
                              void* d_out, int out_size, void* d_ws, size_t ws_size,
                              hipStream_t stream) {
  const float* x      = (const float*)d_in[0];
  const int*   ei     = (const int*)d_in[1];
  const int*   batch  = (const int*)d_in[2];
  const float* W0     = (const float*)d_in[3];
  const float* gamma0 = (const float*)d_in[5];
  const float* beta0  = (const float*)d_in[6];
  const float* W1     = (const float*)d_in[7];
  const float* gamma1 = (const float*)d_in[9];
  const float* beta1  = (const float*)d_in[10];
  const float* W2     = (const float*)d_in[11];
  const float* gamma2 = (const float*)d_in[13];
  const float* beta2  = (const float*)d_in[14];
  const float* Wl     = (const float*)d_in[15];
  const float* bl     = (const float*)d_in[16];
  float* out = (float*)d_out;

  int N = in_sizes[0] / 128;  // 50000
  int E = in_sizes[1] / 2;    // 800000
  int G = 128;
  int NC = 40;
  int Mpad = ((N + 127) / 128) * 128;  // 50048
  const int* src = ei;
  const int* dst = ei + E;

  char* p = (char*)d_ws;
  auto alloc = [&](size_t bytes) -> void* {
    void* r = (void*)p;
    p += (bytes + 255) & ~(size_t)255;
    return r;
  };
  unsigned short* xb  = (unsigned short*)alloc((size_t)N * 128 * 2);
  unsigned short* hA  = (unsigned short*)alloc((size_t)Mpad * 256 * 2);
  unsigned short* hB  = (unsigned short*)alloc((size_t)Mpad * 256 * 2);
  unsigned short* Wt0 = (unsigned short*)alloc((size_t)256 * 128 * 2);
  unsigned short* Wt1 = (unsigned short*)alloc((size_t)256 * 256 * 2);
  unsigned short* Wt2 = (unsigned short*)alloc((size_t)256 * 256 * 2);
  int2*  csr      = (int2*) alloc((size_t)E * 8);
  int*   cc       = (int*)  alloc((size_t)2 * N * 4);  // counts | cursor
  int*   counts   = cc;
  int*   cursor   = cc + N;
  int*   offs     = (int*)  alloc((size_t)(N + 1) * 4);
  float* dinv     = (float*)alloc((size_t)N * 4);
  int*   blkSum   = (int*)  alloc(64 * 4);
  int*   blkOff   = (int*)  alloc(64 * 4);
  float* sums     = (float*)alloc(512 * 4);
  float* sumsq    = sums + 256;
  float* scale0   = (float*)alloc(256 * 4);
  float* shift0   = (float*)alloc(256 * 4);
  float* scale1   = (float*)alloc(256 * 4);
  float* shift1   = (float*)alloc(256 * 4);
  float* scale2   = (float*)alloc(256 * 4);
  float* shift2   = (float*)alloc(256 * 4);
  unsigned int* gstart = (unsigned int*)alloc((size_t)(G + 1) * 4);
  float* pool_part = (float*)alloc((size_t)G * PSLICES * 256 * 4);

  // ---- graph structure (once per launch) ----
  hipMemsetAsync(cc, 0, (size_t)2 * N * 4, stream);
  hipMemsetAsync(gstart, 0xFF, (size_t)(G + 1) * 4, stream);
  hipMemsetAsync(sums, 0, 512 * 4, stream);
  // zero hA's pad rows in both channel layouts (128-ch used by layer-0 GEMM,
  // 256-ch used by layer-1/2 GEMMs); pad rows then feed exact zeros into
  // MFMA + BN stats, removing all M-guards.
  hipMemsetAsync(hA + (size_t)N * 128, 0, (size_t)(Mpad - N) * 128 * 2, stream);
  hipMemsetAsync(hA + (size_t)N * 256, 0, (size_t)(Mpad - N) * 256 * 2, stream);
  count_kernel<<<(E + 255) / 256, 256, 0, stream>>>(dst, E, counts);
  int nb = (N + 1023) / 1024;
  scan1<<<nb, 256, 0, stream>>>(counts, N, offs, blkSum, dinv);
  scan2<<<1, 1, 0, stream>>>(blkSum, nb, blkOff, offs, N);
  scan3<<<nb, 1024, 0, stream>>>(offs, N, blkOff);
  fill_kernel<<<(E + 255) / 256, 256, 0, stream>>>(src, dst, E, offs, cursor, dinv, csr);
  boundary_kernel<<<(N + 255) / 256, 256, 0, stream>>>(batch, N, gstart);
  fixup_kernel<<<1, 1, 0, stream>>>(gstart, N, G);

  // ---- dtype prep ----
  cvt_x_kernel<<<(N * 128 / 4 + 255) / 256, 256, 0, stream>>>(x, xb, N * 128 / 4);
  cvtW_kernel<<<(128 * 256 + 255) / 256, 256, 0, stream>>>(W0, Wt0, 128);
  cvtW_kernel<<<(256 * 256 + 255) / 256, 256, 0, stream>>>(W1, Wt1, 256);
  cvtW_kernel<<<(256 * 256 + 255) / 256, 256, 0, stream>>>(W2, Wt2, 256);

  int aggBlocks = (N + 3) / 4;
  dim3 gemmGrid(Mpad / 128, 2);

  // ---- layer 0 ----
  agg128_bf<<<aggBlocks, 256, 0, stream>>>(xb, offs, csr, dinv, hA, N);
  gemm_bf<<<gemmGrid, 256, 0, stream>>>(hA, Wt0, hB, 128, sums, sumsq);
  bn_finalize<<<1, 256, 0, stream>>>(sums, sumsq, gamma0, beta0, N, scale0, shift0);

  // ---- layer 1 (BN0+ReLU fused into gather) ----
  agg256_bf<true><<<aggBlocks, 256, 0, stream>>>(hB, offs, csr, dinv, scale0, shift0, hA, N);
  gemm_bf<<<gemmGrid, 256, 0, stream>>>(hA, Wt1, hB, 256, sums, sumsq);
  bn_finalize<<<1, 256, 0, stream>>>(sums, sumsq, gamma1, beta1, N, scale1, shift1);

  // ---- layer 2 ----
  agg256_bf<true><<<aggBlocks, 256, 0, stream>>>(hB, offs, csr, dinv, scale1, shift1, hA, N);
  gemm_bf<<<gemmGrid, 256, 0, stream>>>(hA, Wt2, hB, 256, sums, sumsq);
  bn_finalize<<<1, 256, 0, stream>>>(sums, sumsq, gamma2, beta2, N, scale2, shift2);

  // ---- pool + classifier ----
  pool_part_bf<<<G * PSLICES, 256, 0, stream>>>(hB, gstart, scale2, shift2, pool_part);
  final_kernel<<<G, 64, 0, stream>>>(pool_part, gstart, Wl, bl, out, NC);
}

// Round 6
// 509.566 us; speedup vs baseline: 2.3569x; 1.0263x over previous
//
#include <hip/hip_runtime.h>

#define BN_EPS 1e-5f

typedef __attribute__((ext_vector_type(8))) short bf16x8;
typedef __attribute__((ext_vector_type(4))) float f32x4;

__device__ __forceinline__ float bf2f(unsigned short u) {
  return __uint_as_float(((unsigned int)u) << 16);
}
__device__ __forceinline__ unsigned short f2bf(float f) {
  unsigned int u = __float_as_uint(f);
  u = u + 0x7FFFu + ((u >> 16) & 1u);   // round-to-nearest-even
  return (unsigned short)(u >> 16);
}

// async global->LDS, 16B per lane; LDS dest = (wave-uniform base) + lane*16
__device__ __forceinline__ void gload16(const unsigned short* g, unsigned short* l) {
  __builtin_amdgcn_global_load_lds(
      (const __attribute__((address_space(1))) unsigned int*)g,
      (__attribute__((address_space(3))) unsigned int*)l, 16, 0, 0);
}

// ---------------- graph structure ----------------

// count in-degree (atomics, random -> no hotspot) + graph-id boundary detect
__global__ __launch_bounds__(256) void count_boundary(const int* __restrict__ dst, int E,
                                                      int* __restrict__ counts,
                                                      const int* __restrict__ batch, int N,
                                                      unsigned int* __restrict__ gstart) {
  int e = blockIdx.x * 256 + threadIdx.x;
  if (e < E) atomicAdd(&counts[dst[e]], 1);
  if (e < N) {
    if (e == 0 || batch[e] != batch[e - 1]) atomicMin(&gstart[batch[e]], (unsigned int)e);
  }
}

// scan1 also produces dinv = rsqrt(deg+1) in the same pass over counts
__global__ __launch_bounds__(256) void scan1(const int* __restrict__ counts, int N,
                                             int* __restrict__ offs, int* __restrict__ blkSum,
                                             float* __restrict__ dinv) {
  __shared__ int sd[256];
  int t = threadIdx.x;
  int i0 = blockIdx.x * 1024 + t * 4;
  int v0 = (i0 + 0 < N) ? counts[i0 + 0] : 0;
  int v1 = (i0 + 1 < N) ? counts[i0 + 1] : 0;
  int v2 = (i0 + 2 < N) ? counts[i0 + 2] : 0;
  int v3 = (i0 + 3 < N) ? counts[i0 + 3] : 0;
  if (i0 + 0 < N) dinv[i0 + 0] = rsqrtf((float)(v0 + 1));
  if (i0 + 1 < N) dinv[i0 + 1] = rsqrtf((float)(v1 + 1));
  if (i0 + 2 < N) dinv[i0 + 2] = rsqrtf((float)(v2 + 1));
  if (i0 + 3 < N) dinv[i0 + 3] = rsqrtf((float)(v3 + 1));
  int tot = v0 + v1 + v2 + v3;
  sd[t] = tot;
  __syncthreads();
  for (int off = 1; off < 256; off <<= 1) {
    int x = (t >= off) ? sd[t - off] : 0;
    __syncthreads();
    sd[t] += x;
    __syncthreads();
  }
  int excl = sd[t] - tot;
  if (i0 + 0 < N) offs[i0 + 0] = excl;
  if (i0 + 1 < N) offs[i0 + 1] = excl + v0;
  if (i0 + 2 < N) offs[i0 + 2] = excl + v0 + v1;
  if (i0 + 3 < N) offs[i0 + 3] = excl + v0 + v1 + v2;
  if (t == 255) blkSum[blockIdx.x] = sd[255];
}

// thread 0: block-sum scan; thread 1: gstart fixup (independent serial tasks)
__global__ void scan2_fix(const int* __restrict__ blkSum, int nb, int* __restrict__ blkOff,
                          int* __restrict__ offs, int N,
                          unsigned int* __restrict__ gstart, int G) {
  if (blockIdx.x != 0) return;
  if (threadIdx.x == 0) {
    int run = 0;
    for (int b = 0; b < nb; ++b) { blkOff[b] = run; run += blkSum[b]; }
    offs[N] = run;
  } else if (threadIdx.x == 1) {
    gstart[G] = (unsigned int)N;
    for (int g = G - 1; g >= 0; --g)
      if (gstart[g] == 0xFFFFFFFFu) gstart[g] = gstart[g + 1];
  }
}

__global__ __launch_bounds__(1024) void scan3(int* __restrict__ offs, int N,
                                              const int* __restrict__ blkOff) {
  int i = blockIdx.x * 1024 + threadIdx.x;
  if (i < N) offs[i] += blkOff[blockIdx.x];
}

// ---------------- fill CSR + all dtype conversions + pad zeroing (one dispatch) ----------------

__global__ __launch_bounds__(256) void fill_cvt(const int* __restrict__ src,
                                                const int* __restrict__ dst, int E,
                                                const int* __restrict__ offs,
                                                int* __restrict__ cursor,
                                                const float* __restrict__ dinv,
                                                int2* __restrict__ csr,
                                                const float* __restrict__ x,
                                                unsigned short* __restrict__ xb, int nx4,
                                                const float* __restrict__ W0,
                                                unsigned short* __restrict__ Wt0,
                                                const float* __restrict__ W1,
                                                unsigned short* __restrict__ Wt1,
                                                const float* __restrict__ W2,
                                                unsigned short* __restrict__ Wt2,
                                                unsigned short* __restrict__ pad128, int npad128_8,
                                                unsigned short* __restrict__ pad256, int npad256_8) {
  long long idx = (long long)blockIdx.x * 256 + threadIdx.x;
  if (idx < E) {
    int e = (int)idx;
    int s = src[e], d = dst[e];
    int pos = offs[d] + atomicAdd(&cursor[d], 1);
    csr[pos] = make_int2(s, __float_as_int(dinv[s] * dinv[d]));
    return;
  }
  idx -= E;
  if (idx < nx4) {  // x f32 -> bf16, 4 elems/thread
    float4 v = ((const float4*)x)[idx];
    unsigned int lo = (unsigned int)f2bf(v.x) | ((unsigned int)f2bf(v.y) << 16);
    unsigned int hi = (unsigned int)f2bf(v.z) | ((unsigned int)f2bf(v.w) << 16);
    ((uint2*)xb)[idx] = make_uint2(lo, hi);
    return;
  }
  idx -= nx4;
  if (idx < 128 * 256) {  // W0[128][256] -> Wt0[256][128]
    int k = (int)(idx >> 8), n = (int)(idx & 255);
    Wt0[n * 128 + k] = f2bf(W0[k * 256 + n]);
    return;
  }
  idx -= 128 * 256;
  if (idx < 256 * 256) {
    int k = (int)(idx >> 8), n = (int)(idx & 255);
    Wt1[n * 256 + k] = f2bf(W1[k * 256 + n]);
    return;
  }
  idx -= 256 * 256;
  if (idx < 256 * 256) {
    int k = (int)(idx >> 8), n = (int)(idx & 255);
    Wt2[n * 256 + k] = f2bf(W2[k * 256 + n]);
    return;
  }
  idx -= 256 * 256;
  if (idx < npad128_8) { ((uint4*)pad128)[idx] = make_uint4(0, 0, 0, 0); return; }
  idx -= npad128_8;
  if (idx < npad256_8) { ((uint4*)pad256)[idx] = make_uint4(0, 0, 0, 0); return; }
}

// ---------------- aggregation (gather, CSR by dst), one wave per node ----------------
// agg256: always applies previous layer's BN+ReLU, with scale/shift computed
// in-block from the fused GEMM stats (replaces bn_finalize kernel).

__device__ __forceinline__ void acc256(uint2 v, float co, float4 sc, float4 sh,
                                       float& ax, float& ay, float& az, float& aw) {
  float fx = fmaxf(bf2f((unsigned short)(v.x & 0xffff)) * sc.x + sh.x, 0.f);
  float fy = fmaxf(bf2f((unsigned short)(v.x >> 16)) * sc.y + sh.y, 0.f);
  float fz = fmaxf(bf2f((unsigned short)(v.y & 0xffff)) * sc.z + sh.z, 0.f);
  float fw = fmaxf(bf2f((unsigned short)(v.y >> 16)) * sc.w + sh.w, 0.f);
  ax += co * fx; ay += co * fy; az += co * fz; aw += co * fw;
}

__global__ __launch_bounds__(256) void agg256_bf(const unsigned short* __restrict__ h,
                                                 const int* __restrict__ offs,
                                                 const int2* __restrict__ csr,
                                                 const float* __restrict__ dinv,
                                                 const float* __restrict__ sums,
                                                 const float* __restrict__ sumsq,
                                                 const float* __restrict__ gamma,
                                                 const float* __restrict__ beta,
                                                 float invN,
                                                 unsigned short* __restrict__ out, int N) {
  __shared__ float s_sc[256], s_sh[256];
  {
    int c = threadIdx.x;
    float mean = sums[c] * invN;
    float var = sumsq[c] * invN - mean * mean;
    float scv = gamma[c] * rsqrtf(var + BN_EPS);
    s_sc[c] = scv;
    s_sh[c] = beta[c] - mean * scv;
  }
  __syncthreads();
  int n = (blockIdx.x * 256 + threadIdx.x) >> 6;
  int lane = threadIdx.x & 63;
  if (n >= N) return;
  float4 sc = *(const float4*)&s_sc[lane * 4];
  float4 sh = *(const float4*)&s_sh[lane * 4];
  float di = dinv[n];
  float self = di * di;
  float ax0 = 0.f, ay0 = 0.f, az0 = 0.f, aw0 = 0.f;
  float ax1 = 0.f, ay1 = 0.f, az1 = 0.f, aw1 = 0.f;
  {
    uint2 v = *((const uint2*)(h + (size_t)n * 256) + lane);
    acc256(v, self, sc, sh, ax0, ay0, az0, aw0);
  }
  int e0 = offs[n], e1 = offs[n + 1];
  for (int eb = e0; eb < e1; eb += 64) {
    int k = min(64, e1 - eb);
    int2 me = make_int2(0, 0);
    if (lane < k) me = csr[eb + lane];
    int i = 0;
    for (; i + 4 <= k; i += 4) {
      int s0 = __shfl(me.x, i),     s1 = __shfl(me.x, i + 1);
      int s2 = __shfl(me.x, i + 2), s3 = __shfl(me.x, i + 3);
      float co0 = __int_as_float(__shfl(me.y, i));
      float co1 = __int_as_float(__shfl(me.y, i + 1));
      float co2 = __int_as_float(__shfl(me.y, i + 2));
      float co3 = __int_as_float(__shfl(me.y, i + 3));
      uint2 v0 = *((const uint2*)(h + (size_t)s0 * 256) + lane);
      uint2 v1 = *((const uint2*)(h + (size_t)s1 * 256) + lane);
      uint2 v2 = *((const uint2*)(h + (size_t)s2 * 256) + lane);
      uint2 v3 = *((const uint2*)(h + (size_t)s3 * 256) + lane);
      acc256(v0, co0, sc, sh, ax0, ay0, az0, aw0);
      acc256(v1, co1, sc, sh, ax1, ay1, az1, aw1);
      acc256(v2, co2, sc, sh, ax0, ay0, az0, aw0);
      acc256(v3, co3, sc, sh, ax1, ay1, az1, aw1);
    }
    for (; i < k; ++i) {
      int s = __shfl(me.x, i);
      float co = __int_as_float(__shfl(me.y, i));
      uint2 v = *((const uint2*)(h + (size_t)s * 256) + lane);
      acc256(v, co, sc, sh, ax0, ay0, az0, aw0);
    }
  }
  float ax = ax0 + ax1, ay = ay0 + ay1, az = az0 + az1, aw = aw0 + aw1;
  unsigned int lo = (unsigned int)f2bf(ax) | ((unsigned int)f2bf(ay) << 16);
  unsigned int hi = (unsigned int)f2bf(az) | ((unsigned int)f2bf(aw) << 16);
  *((uint2*)(out + (size_t)n * 256) + lane) = make_uint2(lo, hi);
}

__device__ __forceinline__ void acc128(unsigned int v, float co, float& ax, float& ay) {
  ax += co * bf2f((unsigned short)(v & 0xffff));
  ay += co * bf2f((unsigned short)(v >> 16));
}

__global__ __launch_bounds__(256) void agg128_bf(const unsigned short* __restrict__ h,
                                                 const int* __restrict__ offs,
                                                 const int2* __restrict__ csr,
                                                 const float* __restrict__ dinv,
                                                 unsigned short* __restrict__ out, int N) {
  int n = (blockIdx.x * 256 + threadIdx.x) >> 6;
  int lane = threadIdx.x & 63;
  if (n >= N) return;
  float di = dinv[n];
  float self = di * di;
  float ax0 = 0.f, ay0 = 0.f, ax1 = 0.f, ay1 = 0.f;
  {
    unsigned int v = *((const unsigned int*)(h + (size_t)n * 128) + lane);
    acc128(v, self, ax0, ay0);
  }
  int e0 = offs[n], e1 = offs[n + 1];
  for (int eb = e0; eb < e1; eb += 64) {
    int k = min(64, e1 - eb);
    int2 me = make_int2(0, 0);
    if (lane < k) me = csr[eb + lane];
    int i = 0;
    for (; i + 4 <= k; i += 4) {
      int s0 = __shfl(me.x, i),     s1 = __shfl(me.x, i + 1);
      int s2 = __shfl(me.x, i + 2), s3 = __shfl(me.x, i + 3);
      float co0 = __int_as_float(__shfl(me.y, i));
      float co1 = __int_as_float(__shfl(me.y, i + 1));
      float co2 = __int_as_float(__shfl(me.y, i + 2));
      float co3 = __int_as_float(__shfl(me.y, i + 3));
      unsigned int v0 = *((const unsigned int*)(h + (size_t)s0 * 128) + lane);
      unsigned int v1 = *((const unsigned int*)(h + (size_t)s1 * 128) + lane);
      unsigned int v2 = *((const unsigned int*)(h + (size_t)s2 * 128) + lane);
      unsigned int v3 = *((const unsigned int*)(h + (size_t)s3 * 128) + lane);
      acc128(v0, co0, ax0, ay0); acc128(v1, co1, ax1, ay1);
      acc128(v2, co2, ax0, ay0); acc128(v3, co3, ax1, ay1);
    }
    for (; i < k; ++i) {
      int s = __shfl(me.x, i);
      float co = __int_as_float(__shfl(me.y, i));
      unsigned int v = *((const unsigned int*)(h + (size_t)s * 128) + lane);
      acc128(v, co, ax0, ay0);
    }
  }
  float ax = ax0 + ax1, ay = ay0 + ay1;
  *((unsigned int*)(out + (size_t)n * 128) + lane) =
      (unsigned int)f2bf(ax) | ((unsigned int)f2bf(ay) << 16);
}

// ---------------- bf16 MFMA GEMM + fused BN partial stats ----------------
// C[Mpad,256] = A[Mpad,K] @ W[K,256]; 128x128 tile, BK=64, 4 waves 2x2.
// global_load_lds staging, XOR-pre-swizzled source + swizzled reads (conflict-free).
// Pad rows are zero -> no guards, exact-zero contribution to stats.

__global__ __launch_bounds__(256) void gemm_bf(const unsigned short* __restrict__ A,
                                               const unsigned short* __restrict__ Wt,
                                               unsigned short* __restrict__ C,
                                               int K,
                                               float* __restrict__ sums,
                                               float* __restrict__ sumsq) {
  __shared__ unsigned short As[128 * 64];
  __shared__ unsigned short Bs[128 * 64];
  int t = threadIdx.x;
  int w = t >> 6, lane = t & 63;
  int l16 = lane & 15, lhi = lane >> 4;
  int wr = w >> 1, wc = w & 1;
  int rowBase = blockIdx.x * 128, colBase = blockIdx.y * 128;
  f32x4 acc[4][4] = {};
  int srow = lane >> 3;   // 0..7 within 8-row segment
  int sg = lane & 7;      // 16B group within 128B row
  const unsigned short* Abase = A + (size_t)rowBase * K;
  const unsigned short* Bbase = Wt + (size_t)colBase * K;
  for (int k0 = 0; k0 < K; k0 += 64) {
#pragma unroll
    for (int i = 0; i < 4; ++i) {
      int rb = i * 32 + w * 8;          // segment base row (wave-uniform)
      int row = rb + srow;
      int gg = sg ^ (row & 7);          // pre-swizzled source group
      gload16(Abase + (size_t)row * K + k0 + gg * 8, &As[rb * 64]);
      gload16(Bbase + (size_t)row * K + k0 + gg * 8, &Bs[rb * 64]);
    }
    __syncthreads();
#pragma unroll
    for (int kk = 0; kk < 64; kk += 32) {
      int gb = (kk >> 3) + lhi;
      bf16x8 a[4], b[4];
#pragma unroll
      for (int i = 0; i < 4; ++i) {
        int ra = wr * 64 + i * 16 + l16;
        a[i] = *(const bf16x8*)&As[ra * 64 + ((gb ^ (ra & 7)) << 3)];
        int rb2 = wc * 64 + i * 16 + l16;
        b[i] = *(const bf16x8*)&Bs[rb2 * 64 + ((gb ^ (rb2 & 7)) << 3)];
      }
#pragma unroll
      for (int i = 0; i < 4; ++i)
#pragma unroll
        for (int j = 0; j < 4; ++j)
          acc[i][j] = __builtin_amdgcn_mfma_f32_16x16x32_bf16(a[i], b[j], acc[i][j], 0, 0, 0);
    }
    __syncthreads();
  }
#pragma unroll
  for (int i = 0; i < 4; ++i) {
#pragma unroll
    for (int rr = 0; rr < 4; ++rr) {
      int row = rowBase + wr * 64 + i * 16 + lhi * 4 + rr;
      size_t o = (size_t)row * 256 + colBase + wc * 64 + l16;
#pragma unroll
      for (int j = 0; j < 4; ++j) C[o + j * 16] = f2bf(acc[i][j][rr]);
    }
  }
#pragma unroll
  for (int j = 0; j < 4; ++j) {
    float s = 0.f, s2 = 0.f;
#pragma unroll
    for (int i = 0; i < 4; ++i)
#pragma unroll
      for (int rr = 0; rr < 4; ++rr) { float v = acc[i][j][rr]; s += v; s2 += v * v; }
    s  += __shfl_xor(s, 16);  s  += __shfl_xor(s, 32);
    s2 += __shfl_xor(s2, 16); s2 += __shfl_xor(s2, 32);
    if (lhi == 0) {
      int col = colBase + wc * 64 + j * 16 + l16;
      atomicAdd(&sums[col], s);
      atomicAdd(&sumsq[col], s2);
    }
  }
}

// ---------------- pool (BN2+ReLU fused, in-block finalize) + classifier ----------------
// One block per graph: wave w takes rows gs+w, step 4; lane holds 4 channels.

__global__ __launch_bounds__(256) void pool_final(const unsigned short* __restrict__ h,
                                                  const unsigned int* __restrict__ gstart,
                                                  const float* __restrict__ sums,
                                                  const float* __restrict__ sumsq,
                                                  const float* __restrict__ gamma,
                                                  const float* __restrict__ beta,
                                                  float invN,
                                                  const float* __restrict__ Wl,
                                                  const float* __restrict__ bl,
                                                  float* __restrict__ out, int NC) {
  __shared__ float s_sc[256], s_sh[256];
  __shared__ float4 part[4][64];
  __shared__ float p[256];
  int t = threadIdx.x, w = t >> 6, lane = t & 63;
  {
    float mean = sums[t] * invN;
    float var = sumsq[t] * invN - mean * mean;
    float scv = gamma[t] * rsqrtf(var + BN_EPS);
    s_sc[t] = scv;
    s_sh[t] = beta[t] - mean * scv;
  }
  __syncthreads();
  float4 sc = *(const float4*)&s_sc[lane * 4];
  float4 sh = *(const float4*)&s_sh[lane * 4];
  int g = blockIdx.x;
  int gs = (int)gstart[g], ge = (int)gstart[g + 1];
  float ax = 0.f, ay = 0.f, az = 0.f, aw = 0.f;
  for (int r = gs + w; r < ge; r += 4) {
    uint2 v = *((const uint2*)(h + (size_t)r * 256) + lane);
    ax += fmaxf(bf2f((unsigned short)(v.x & 0xffff)) * sc.x + sh.x, 0.f);
    ay += fmaxf(bf2f((unsigned short)(v.x >> 16)) * sc.y + sh.y, 0.f);
    az += fmaxf(bf2f((unsigned short)(v.y & 0xffff)) * sc.z + sh.z, 0.f);
    aw += fmaxf(bf2f((unsigned short)(v.y >> 16)) * sc.w + sh.w, 0.f);
  }
  part[w][lane] = make_float4(ax, ay, az, aw);
  __syncthreads();
  if (t < 64) {
    float inv = 1.0f / fmaxf((float)(ge - gs), 1.0f);
    float4 s0 = part[0][t], s1 = part[1][t], s2 = part[2][t], s3 = part[3][t];
    float4 r;
    r.x = (s0.x + s1.x + s2.x + s3.x) * inv;
    r.y = (s0.y + s1.y + s2.y + s3.y) * inv;
    r.z = (s0.z + s1.z + s2.z + s3.z) * inv;
    r.w = (s0.w + s1.w + s2.w + s3.w) * inv;
    *(float4*)&p[t * 4] = r;
  }
  __syncthreads();
  if (t < NC) {
    float s = bl[t];
    for (int k = 0; k < 256; ++k) s += p[k] * Wl[k * NC + t];
    out[g * NC + t] = s;
  }
}

// ---------------- launcher ----------------

extern "C" void kernel_launch(void* const* d_in, const int* in_sizes, int n_in,
                              void* d_out, int out_size, void* d_ws, size_t ws_size,
                              hipStream_t stream) {
  const float* x      = (const float*)d_in[0];
  const int*   ei     = (const int*)d_in[1];
  const int*   batch  = (const int*)d_in[2];
  const float* W0     = (const float*)d_in[3];
  const float* gamma0 = (const float*)d_in[5];
  const float* beta0  = (const float*)d_in[6];
  const float* W1     = (const float*)d_in[7];
  const float* gamma1 = (const float*)d_in[9];
  const float* beta1  = (const float*)d_in[10];
  const float* W2     = (const float*)d_in[11];
  const float* gamma2 = (const float*)d_in[13];
  const float* beta2  = (const float*)d_in[14];
  const float* Wl     = (const float*)d_in[15];
  const float* bl     = (const float*)d_in[16];
  float* out = (float*)d_out;

  int N = in_sizes[0] / 128;  // 50000
  int E = in_sizes[1] / 2;    // 800000
  int G = 128;
  int NC = 40;
  int Mpad = ((N + 127) / 128) * 128;  // 50048
  float invN = 1.0f / (float)N;
  const int* src = ei;
  const int* dst = ei + E;

  char* p = (char*)d_ws;
  auto alloc = [&](size_t bytes) -> void* {
    void* r = (void*)p;
    p += (bytes + 255) & ~(size_t)255;
    return r;
  };
  unsigned short* xb  = (unsigned short*)alloc((size_t)N * 128 * 2);
  unsigned short* hA  = (unsigned short*)alloc((size_t)Mpad * 256 * 2);
  unsigned short* hB  = (unsigned short*)alloc((size_t)Mpad * 256 * 2);
  unsigned short* Wt0 = (unsigned short*)alloc((size_t)256 * 128 * 2);
  unsigned short* Wt1 = (unsigned short*)alloc((size_t)256 * 256 * 2);
  unsigned short* Wt2 = (unsigned short*)alloc((size_t)256 * 256 * 2);
  int2*  csr      = (int2*) alloc((size_t)E * 8);
  // counts | cursor | 3x(sums,sumsq) — zeroed with ONE memset
  int*   cc       = (int*)  alloc((size_t)(2 * N + 6 * 256) * 4);
  int*   counts   = cc;
  int*   cursor   = cc + N;
  float* stats    = (float*)(cc + 2 * N);
  float* sums0 = stats + 0 * 256, *sumsq0 = stats + 1 * 256;
  float* sums1 = stats + 2 * 256, *sumsq1 = stats + 3 * 256;
  float* sums2 = stats + 4 * 256, *sumsq2 = stats + 5 * 256;
  int*   offs     = (int*)  alloc((size_t)(N + 1) * 4);
  float* dinv     = (float*)alloc((size_t)N * 4);
  int*   blkSum   = (int*)  alloc(64 * 4);
  int*   blkOff   = (int*)  alloc(64 * 4);
  unsigned int* gstart = (unsigned int*)alloc((size_t)(G + 1) * 4);

  // ---- init (2 memsets) ----
  hipMemsetAsync(cc, 0, (size_t)(2 * N + 6 * 256) * 4, stream);
  hipMemsetAsync(gstart, 0xFF, (size_t)(G + 1) * 4, stream);

  // ---- graph structure ----
  count_boundary<<<(E + 255) / 256, 256, 0, stream>>>(dst, E, counts, batch, N, gstart);
  int nb = (N + 1023) / 1024;
  scan1<<<nb, 256, 0, stream>>>(counts, N, offs, blkSum, dinv);
  scan2_fix<<<1, 64, 0, stream>>>(blkSum, nb, blkOff, offs, N, gstart, G);
  scan3<<<nb, 1024, 0, stream>>>(offs, N, blkOff);

  // ---- fill CSR + all conversions + pad zeroing (one dispatch) ----
  {
    int nx4 = N * 32;                       // N*128/4 quads
    int npad128_8 = (Mpad - N) * 128 / 8;
    int npad256_8 = (Mpad - N) * 256 / 8;
    long long total = (long long)E + nx4 + 128 * 256 + 256 * 256 + 256 * 256
                    + npad128_8 + npad256_8;
    int blocks = (int)((total + 255) / 256);
    fill_cvt<<<blocks, 256, 0, stream>>>(src, dst, E, offs, cursor, dinv, csr,
                                         x, xb, nx4, W0, Wt0, W1, Wt1, W2, Wt2,
                                         hA + (size_t)N * 128, npad128_8,
                                         hA + (size_t)N * 256, npad256_8);
  }

  int aggBlocks = (N + 3) / 4;
  dim3 gemmGrid(Mpad / 128, 2);

  // ---- layer 0 ----
  agg128_bf<<<aggBlocks, 256, 0, stream>>>(xb, offs, csr, dinv, hA, N);
  gemm_bf<<<gemmGrid, 256, 0, stream>>>(hA, Wt0, hB, 128, sums0, sumsq0);

  // ---- layer 1 (BN0 finalize + ReLU fused into gather prologue) ----
  agg256_bf<<<aggBlocks, 256, 0, stream>>>(hB, offs, csr, dinv, sums0, sumsq0,
                                           gamma0, beta0, invN, hA, N);
  gemm_bf<<<gemmGrid, 256, 0, stream>>>(hA, Wt1, hB, 256, sums1, sumsq1);

  // ---- layer 2 ----
  agg256_bf<<<aggBlocks, 256, 0, stream>>>(hB, offs, csr, dinv, sums1, sumsq1,
                                           gamma1, beta1, invN, hA, N);
  gemm_bf<<<gemmGrid, 256, 0, stream>>>(hA, Wt2, hB, 256, sums2, sumsq2);

  // ---- pool (BN2 finalize in-block) + classifier ----
  pool_final<<<G, 256, 0, stream>>>(hB, gstart, sums2, sumsq2, gamma2, beta2, invN,
                                    Wl, bl, out, NC);
}